// Round 1
// baseline (1420.354 us; speedup 1.0000x reference)
//
#include <hip/hip_runtime.h>
#include <hip/hip_bf16.h>
#include <math.h>

#define T_SEQ 2048
#define HID   2048
#define NH    16
#define NKV   8
#define DH    128
#define QKV_N (NH*DH + 2*NKV*DH)   // 4096
#define KOFF  (NH*DH)              // 2048
#define VOFF  ((NH+NKV)*DH)        // 3072
#define EPS_RMS 1e-6f
#define ATT_SCALE 0.08838834764831845f   // 128^-0.5

// ---------------------------------------------------------------------------
// GEMM fp32: C[M,N] = A[M,K] @ B[K,N], all row-major. 128x128 tile, BK=16,
// 256 threads, 8x8 micro-tile per thread.
// ---------------------------------------------------------------------------
__global__ __launch_bounds__(256)
void gemm_f32(const float* __restrict__ A, const float* __restrict__ B,
              float* __restrict__ C, int M, int N, int K) {
  __shared__ float As[16][132];   // As[k][m], +4 pad
  __shared__ float Bs[16][132];   // Bs[k][n], +4 pad

  const int t  = threadIdx.x;
  const int tx = t & 15;          // 0..15
  const int ty = t >> 4;          // 0..15
  const int bm = blockIdx.y * 128;
  const int bn = blockIdx.x * 128;

  float acc[8][8];
#pragma unroll
  for (int i = 0; i < 8; ++i)
#pragma unroll
    for (int j = 0; j < 8; ++j) acc[i][j] = 0.0f;

  for (int k0 = 0; k0 < K; k0 += 16) {
    // stage A tile (128 rows x 16 k) and B tile (16 k x 128 n)
#pragma unroll
    for (int it = 0; it < 2; ++it) {
      const int f = it * 256 + t;               // 0..511
      // A: float4 along K, transposed store into As[k][m]
      {
        const int m  = f >> 2;
        const int k4 = (f & 3) * 4;
        const float4 av = *(const float4*)(A + (size_t)(bm + m) * K + k0 + k4);
        As[k4 + 0][m] = av.x;
        As[k4 + 1][m] = av.y;
        As[k4 + 2][m] = av.z;
        As[k4 + 3][m] = av.w;
      }
      // B: float4 along N, direct store
      {
        const int kb = f >> 5;
        const int n4 = (f & 31) * 4;
        *(float4*)&Bs[kb][n4] = *(const float4*)(B + (size_t)(k0 + kb) * N + bn + n4);
      }
    }
    __syncthreads();

#pragma unroll
    for (int kk = 0; kk < 16; ++kk) {
      const float4 a0 = *(const float4*)&As[kk][ty * 4];
      const float4 a1 = *(const float4*)&As[kk][64 + ty * 4];
      const float4 b0 = *(const float4*)&Bs[kk][tx * 4];
      const float4 b1 = *(const float4*)&Bs[kk][64 + tx * 4];
      const float a[8] = {a0.x, a0.y, a0.z, a0.w, a1.x, a1.y, a1.z, a1.w};
      const float b[8] = {b0.x, b0.y, b0.z, b0.w, b1.x, b1.y, b1.z, b1.w};
#pragma unroll
      for (int i = 0; i < 8; ++i)
#pragma unroll
        for (int j = 0; j < 8; ++j) acc[i][j] = fmaf(a[i], b[j], acc[i][j]);
    }
    __syncthreads();
  }

  // epilogue: rows ty*4+i and 64+ty*4+i ; cols tx*4.. and 64+tx*4..
#pragma unroll
  for (int i = 0; i < 8; ++i) {
    const int m = bm + ((i < 4) ? (ty * 4 + i) : (64 + ty * 4 + (i - 4)));
    const float4 c0 = {acc[i][0], acc[i][1], acc[i][2], acc[i][3]};
    const float4 c1 = {acc[i][4], acc[i][5], acc[i][6], acc[i][7]};
    *(float4*)(C + (size_t)m * N + bn + tx * 4)      = c0;
    *(float4*)(C + (size_t)m * N + bn + 64 + tx * 4) = c1;
  }
}

// ---------------------------------------------------------------------------
// Fused RMSNorm + RoPE, in-place on the q and k regions of qkv.
// One wave (64 lanes) per (t, head); lane l owns elements l and l+64
// (exactly the rotate-half pairing).  heads 0..15 = q, 16..23 = k.
// ---------------------------------------------------------------------------
__global__ __launch_bounds__(256)
void normrope(float* __restrict__ qkv, const int* __restrict__ pos,
              const float* __restrict__ qw, const float* __restrict__ kw) {
  const int wave = threadIdx.x >> 6;
  const int lane = threadIdx.x & 63;
  const int idx  = blockIdx.x * 4 + wave;   // 0 .. T_SEQ*24-1
  const int tt   = idx / 24;
  const int hh   = idx % 24;

  float* base = qkv + (size_t)tt * QKV_N + hh * DH;
  const float x1 = base[lane];
  const float x2 = base[lane + 64];

  float ss = x1 * x1 + x2 * x2;
#pragma unroll
  for (int off = 32; off > 0; off >>= 1) ss += __shfl_xor(ss, off);

  const float inv = rsqrtf(ss * (1.0f / DH) + EPS_RMS);
  const float* w = (hh < NH) ? qw : kw;
  const float n1 = x1 * inv * w[lane];
  const float n2 = x2 * inv * w[lane + 64];

  const float p    = (float)pos[tt];
  const float freq = powf(10000.0f, -(float)lane * (1.0f / 64.0f));
  const float ang  = p * freq;
  const float c = cosf(ang);
  const float s = sinf(ang);

  base[lane]      = n1 * c - n2 * s;
  base[lane + 64] = n2 * c + n1 * s;
}

// ---------------------------------------------------------------------------
// Causal GQA flash attention, fp32.  Q-tile 32 x K-tile 32, 256 threads.
// Thread (ty,tx): S rows {ty*2, ty*2+1}, S cols {tx, tx+16}; O cols
// {tx*4..+3, 64+tx*4..+3}.
// ---------------------------------------------------------------------------
__global__ __launch_bounds__(256)
void flash_attn(const float* __restrict__ qkv, float* __restrict__ obuf) {
  __shared__ float Qs[32][132];
  __shared__ float Ks[32][132];
  __shared__ float Vs[32][132];
  __shared__ float Ps[32][36];

  const int t  = threadIdx.x;
  const int tx = t & 15;
  const int ty = t >> 4;
  const int h  = blockIdx.y;
  const int qt = gridDim.x - 1 - blockIdx.x;   // heavy tiles first
  const int q0 = qt * 32;
  const int kvh = h >> 1;                      // G = 2

  const float* Qg = qkv + h * DH;
  const float* Kg = qkv + KOFF + kvh * DH;
  const float* Vg = qkv + VOFF + kvh * DH;

  // stage Q tile: 32 x 128 floats = 1024 float4, 4 per thread
#pragma unroll
  for (int it = 0; it < 4; ++it) {
    const int f  = it * 256 + t;
    const int r  = f >> 5;
    const int c4 = (f & 31) * 4;
    *(float4*)&Qs[r][c4] = *(const float4*)(Qg + (size_t)(q0 + r) * QKV_N + c4);
  }

  const int r0 = ty * 2;
  float m0 = -INFINITY, m1 = -INFINITY;
  float l0 = 0.0f, l1 = 0.0f;
  float acc0[8], acc1[8];
#pragma unroll
  for (int j = 0; j < 8; ++j) { acc0[j] = 0.0f; acc1[j] = 0.0f; }

  __syncthreads();

  for (int kt = 0; kt <= qt; ++kt) {
    const int k0 = kt * 32;
    // stage K and V tiles
#pragma unroll
    for (int it = 0; it < 4; ++it) {
      const int f  = it * 256 + t;
      const int r  = f >> 5;
      const int c4 = (f & 31) * 4;
      *(float4*)&Ks[r][c4] = *(const float4*)(Kg + (size_t)(k0 + r) * QKV_N + c4);
      *(float4*)&Vs[r][c4] = *(const float4*)(Vg + (size_t)(k0 + r) * QKV_N + c4);
    }
    __syncthreads();

    // S = Q K^T  (2 rows x 2 cols per thread)
    float s00 = 0.f, s01 = 0.f, s10 = 0.f, s11 = 0.f;
#pragma unroll 8
    for (int d4 = 0; d4 < 32; ++d4) {
      const float4 qa = *(const float4*)&Qs[r0][d4 * 4];
      const float4 qb = *(const float4*)&Qs[r0 + 1][d4 * 4];
      const float4 ka = *(const float4*)&Ks[tx][d4 * 4];
      const float4 kb = *(const float4*)&Ks[tx + 16][d4 * 4];
      s00 = fmaf(qa.x, ka.x, s00); s00 = fmaf(qa.y, ka.y, s00);
      s00 = fmaf(qa.z, ka.z, s00); s00 = fmaf(qa.w, ka.w, s00);
      s01 = fmaf(qa.x, kb.x, s01); s01 = fmaf(qa.y, kb.y, s01);
      s01 = fmaf(qa.z, kb.z, s01); s01 = fmaf(qa.w, kb.w, s01);
      s10 = fmaf(qb.x, ka.x, s10); s10 = fmaf(qb.y, ka.y, s10);
      s10 = fmaf(qb.z, ka.z, s10); s10 = fmaf(qb.w, ka.w, s10);
      s11 = fmaf(qb.x, kb.x, s11); s11 = fmaf(qb.y, kb.y, s11);
      s11 = fmaf(qb.z, kb.z, s11); s11 = fmaf(qb.w, kb.w, s11);
    }

    // scale + causal mask
    const int qi0 = q0 + r0, qi1 = q0 + r0 + 1;
    const int kj0 = k0 + tx, kj1 = k0 + tx + 16;
    s00 = (qi0 >= kj0) ? s00 * ATT_SCALE : -INFINITY;
    s01 = (qi0 >= kj1) ? s01 * ATT_SCALE : -INFINITY;
    s10 = (qi1 >= kj0) ? s10 * ATT_SCALE : -INFINITY;
    s11 = (qi1 >= kj1) ? s11 * ATT_SCALE : -INFINITY;

    // online softmax: row max over 16 tx lanes
    float tm0 = fmaxf(s00, s01);
    float tm1 = fmaxf(s10, s11);
#pragma unroll
    for (int off = 8; off > 0; off >>= 1) {
      tm0 = fmaxf(tm0, __shfl_xor(tm0, off));
      tm1 = fmaxf(tm1, __shfl_xor(tm1, off));
    }
    const float mn0 = fmaxf(m0, tm0);
    const float mn1 = fmaxf(m1, tm1);
    const float al0 = expf(m0 - mn0);   // expf(-inf)=0 on first tile
    const float al1 = expf(m1 - mn1);
    const float p00 = expf(s00 - mn0);
    const float p01 = expf(s01 - mn0);
    const float p10 = expf(s10 - mn1);
    const float p11 = expf(s11 - mn1);
    float rs0 = p00 + p01;
    float rs1 = p10 + p11;
#pragma unroll
    for (int off = 8; off > 0; off >>= 1) {
      rs0 += __shfl_xor(rs0, off);
      rs1 += __shfl_xor(rs1, off);
    }
    l0 = l0 * al0 + rs0;
    l1 = l1 * al1 + rs1;
    m0 = mn0;
    m1 = mn1;
#pragma unroll
    for (int j = 0; j < 8; ++j) { acc0[j] *= al0; acc1[j] *= al1; }

    Ps[r0][tx]          = p00;
    Ps[r0][tx + 16]     = p01;
    Ps[r0 + 1][tx]      = p10;
    Ps[r0 + 1][tx + 16] = p11;
    __syncthreads();

    // PV: O += P @ V
#pragma unroll 8
    for (int c = 0; c < 32; ++c) {
      const float p0 = Ps[r0][c];
      const float p1 = Ps[r0 + 1][c];
      const float4 va = *(const float4*)&Vs[c][tx * 4];
      const float4 vb = *(const float4*)&Vs[c][64 + tx * 4];
      acc0[0] = fmaf(p0, va.x, acc0[0]); acc0[1] = fmaf(p0, va.y, acc0[1]);
      acc0[2] = fmaf(p0, va.z, acc0[2]); acc0[3] = fmaf(p0, va.w, acc0[3]);
      acc0[4] = fmaf(p0, vb.x, acc0[4]); acc0[5] = fmaf(p0, vb.y, acc0[5]);
      acc0[6] = fmaf(p0, vb.z, acc0[6]); acc0[7] = fmaf(p0, vb.w, acc0[7]);
      acc1[0] = fmaf(p1, va.x, acc1[0]); acc1[1] = fmaf(p1, va.y, acc1[1]);
      acc1[2] = fmaf(p1, va.z, acc1[2]); acc1[3] = fmaf(p1, va.w, acc1[3]);
      acc1[4] = fmaf(p1, vb.x, acc1[4]); acc1[5] = fmaf(p1, vb.y, acc1[5]);
      acc1[6] = fmaf(p1, vb.z, acc1[6]); acc1[7] = fmaf(p1, vb.w, acc1[7]);
    }
    __syncthreads();
  }

  // epilogue
  const float inv0 = 1.0f / l0;
  const float inv1 = 1.0f / l1;
  float* o0 = obuf + (size_t)(q0 + r0) * HID + h * DH;
  float* o1 = obuf + (size_t)(q0 + r0 + 1) * HID + h * DH;
  const float4 w00 = {acc0[0] * inv0, acc0[1] * inv0, acc0[2] * inv0, acc0[3] * inv0};
  const float4 w01 = {acc0[4] * inv0, acc0[5] * inv0, acc0[6] * inv0, acc0[7] * inv0};
  const float4 w10 = {acc1[0] * inv1, acc1[1] * inv1, acc1[2] * inv1, acc1[3] * inv1};
  const float4 w11 = {acc1[4] * inv1, acc1[5] * inv1, acc1[6] * inv1, acc1[7] * inv1};
  *(float4*)(o0 + tx * 4)      = w00;
  *(float4*)(o0 + 64 + tx * 4) = w01;
  *(float4*)(o1 + tx * 4)      = w10;
  *(float4*)(o1 + 64 + tx * 4) = w11;
}

// ---------------------------------------------------------------------------
extern "C" void kernel_launch(void* const* d_in, const int* in_sizes, int n_in,
                              void* d_out, int out_size, void* d_ws, size_t ws_size,
                              hipStream_t stream) {
  const float* x     = (const float*)d_in[0];
  const int*   pos   = (const int*)d_in[1];
  const float* w_qkv = (const float*)d_in[2];
  const float* qw    = (const float*)d_in[3];
  const float* kw    = (const float*)d_in[4];
  const float* w_o   = (const float*)d_in[5];
  float* out = (float*)d_out;

  float* qkv  = (float*)d_ws;                          // T_SEQ * 4096 floats
  float* obuf = qkv + (size_t)T_SEQ * QKV_N;           // T_SEQ * 2048 floats

  // 1) qkv = x @ w_qkv   (2048 x 4096 x 2048)
  gemm_f32<<<dim3(QKV_N / 128, T_SEQ / 128), 256, 0, stream>>>(
      x, w_qkv, qkv, T_SEQ, QKV_N, HID);

  // 2) fused RMSNorm + RoPE on q,k (in place)
  normrope<<<dim3(T_SEQ * 24 / 4), 256, 0, stream>>>(qkv, pos, qw, kw);

  // 3) causal GQA flash attention -> obuf (T x 2048)
  flash_attn<<<dim3(T_SEQ / 32, NH), 256, 0, stream>>>(qkv, obuf);

  // 4) out = obuf @ w_o  (2048 x 2048 x 2048)
  gemm_f32<<<dim3(HID / 128, T_SEQ / 128), 256, 0, stream>>>(
      obuf, w_o, out, T_SEQ, HID, NH * DH);
}

// Round 4
// 327.227 us; speedup vs baseline: 4.3406x; 4.3406x over previous
//
#include <hip/hip_runtime.h>
#include <hip/hip_bf16.h>
#include <math.h>

#define T_SEQ 2048
#define HID   2048
#define NH    16
#define NKV   8
#define DH    128
#define QKV_N 4096
#define KOFF  2048
#define VOFF  3072
#define EPS_RMS 1e-6f
#define ATT_SCALE 0.08838834764831845f   // 128^-0.5

typedef __attribute__((ext_vector_type(8))) short bf16x8;   // 8 bf16 = 4 VGPR
typedef __attribute__((ext_vector_type(4))) float f32x4;
typedef unsigned short u16;

__device__ __forceinline__ u16 f2b(float f) {               // fp32 -> bf16 RNE
  union { float f; unsigned u; } v; v.f = f;
  unsigned r = v.u + 0x7fff + ((v.u >> 16) & 1);
  return (u16)(r >> 16);
}
__device__ __forceinline__ float b2f(u16 x) {
  union { unsigned u; float f; } v; v.u = ((unsigned)x) << 16;
  return v.f;
}

// async global->LDS, 16B per lane. LDS dest must be linear base + lane*16.
__device__ __forceinline__ void g2l16(u16* l, const u16* g) {
#if __has_builtin(__builtin_amdgcn_global_load_lds)
  __builtin_amdgcn_global_load_lds(
      (const __attribute__((address_space(1))) unsigned int*)g,
      (__attribute__((address_space(3))) unsigned int*)l, 16, 0, 0);
#else
  *(float4*)l = *(const float4*)g;
#endif
}

// ---------------------------------------------------------------------------
// elementwise fp32 -> bf16 cast (x)
// ---------------------------------------------------------------------------
__global__ __launch_bounds__(256)
void cast_bf16(const float* __restrict__ src, u16* __restrict__ dst) {
  const int i = blockIdx.x * 256 + threadIdx.x;
  const float4 v = ((const float4*)src)[i];
  ushort4 o; o.x = f2b(v.x); o.y = f2b(v.y); o.z = f2b(v.z); o.w = f2b(v.w);
  ((ushort4*)dst)[i] = o;
}

// ---------------------------------------------------------------------------
// transpose + cast: src fp32 [R][C] -> dst bf16 [C][R]
// ---------------------------------------------------------------------------
__global__ __launch_bounds__(256)
void tcast(const float* __restrict__ src, u16* __restrict__ dst, int R, int C) {
  __shared__ u16 tile[32][36];
  const int br = blockIdx.y * 32, bc = blockIdx.x * 32;
  const int t = threadIdx.x;
  {
    const int r = t >> 3, c4 = (t & 7) * 4;
    const float4 v = *(const float4*)(src + (size_t)(br + r) * C + bc + c4);
    tile[c4 + 0][r] = f2b(v.x);
    tile[c4 + 1][r] = f2b(v.y);
    tile[c4 + 2][r] = f2b(v.z);
    tile[c4 + 3][r] = f2b(v.w);
  }
  __syncthreads();
  {
    const int c = t >> 3, r4 = (t & 7) * 4;
    ushort4 o = { tile[c][r4], tile[c][r4 + 1], tile[c][r4 + 2], tile[c][r4 + 3] };
    *(ushort4*)(dst + (size_t)(bc + c) * R + br + r4) = o;
  }
}

// ---------------------------------------------------------------------------
// bf16 MFMA GEMM: C[M][N] = A[M][K] @ BT[N][K]^T.  128x128 tile, BK=32,
// 4 waves, 4x4 16x16x32 fragments per wave.  BOUT: 1 = bf16 out, 0 = fp32.
// ---------------------------------------------------------------------------
template<int BOUT>
__global__ __launch_bounds__(256)
void gemm_bt(const u16* __restrict__ A, const u16* __restrict__ BT,
             void* __restrict__ Cout, int M, int N, int K) {
  __shared__ u16 sA[128 * 32];   // [row][32 k] linear, 8 KB
  __shared__ u16 sB[128 * 32];

  const int t = threadIdx.x;
  const int lane = t & 63, wv = t >> 6;
  const int lo = lane & 15, hi = lane >> 4;
  const int bm = blockIdx.y * 128, bn = blockIdx.x * 128;
  const int wr = (wv >> 1) * 64, wc = (wv & 1) * 64;

  f32x4 acc[4][4];
#pragma unroll
  for (int m = 0; m < 4; ++m)
#pragma unroll
    for (int n = 0; n < 4; ++n) acc[m][n] = (f32x4){0.f, 0.f, 0.f, 0.f};

  // staging: wave wv fills LDS chunks {2wv, 2wv+1} (1 KB each = 16 rows)
  const int arow = wv * 32 + (lane >> 2);        // row for call 0
  const int koff = (lane & 3) * 8;               // bf16 offset in row
  const u16* gA = A + (size_t)(bm + arow) * K + koff;
  const u16* gB = BT + (size_t)(bn + arow) * K + koff;
  u16* lA = sA + wv * 1024 + lane * 8;
  u16* lB = sB + wv * 1024 + lane * 8;

  for (int k0 = 0; k0 < K; k0 += 32) {
    g2l16(lA,       gA + k0);
    g2l16(lA + 512, gA + (size_t)16 * K + k0);
    g2l16(lB,       gB + k0);
    g2l16(lB + 512, gB + (size_t)16 * K + k0);
    __syncthreads();

    bf16x8 af[4], bfr[4];
#pragma unroll
    for (int m = 0; m < 4; ++m)
      af[m] = *(const bf16x8*)(sA + (wr + m * 16 + lo) * 32 + hi * 8);
#pragma unroll
    for (int n = 0; n < 4; ++n)
      bfr[n] = *(const bf16x8*)(sB + (wc + n * 16 + lo) * 32 + hi * 8);
#pragma unroll
    for (int m = 0; m < 4; ++m)
#pragma unroll
      for (int n = 0; n < 4; ++n)
        acc[m][n] = __builtin_amdgcn_mfma_f32_16x16x32_bf16(af[m], bfr[n], acc[m][n], 0, 0, 0);
    __syncthreads();
  }

  // D layout: row = hi*4 + reg, col = lo
#pragma unroll
  for (int m = 0; m < 4; ++m)
#pragma unroll
    for (int n = 0; n < 4; ++n)
#pragma unroll
      for (int r = 0; r < 4; ++r) {
        const int row = bm + wr + m * 16 + hi * 4 + r;
        const int col = bn + wc + n * 16 + lo;
        if constexpr (BOUT)
          ((u16*)Cout)[(size_t)row * N + col] = f2b(acc[m][n][r]);
        else
          ((float*)Cout)[(size_t)row * N + col] = acc[m][n][r];
      }
}

// ---------------------------------------------------------------------------
// RMSNorm + RoPE on q,k (bf16 in, bf16 out). One wave per (t, head).
// q -> qbf [T][NH][128] row-major.
// k -> kbf [T][NKV][128] with d pre-swizzled: pos = d ^ ((t&7)<<3)
//      (so flash's linear global_load_lds lands XOR-swizzled in LDS).
// ---------------------------------------------------------------------------
__global__ __launch_bounds__(256)
void normrope(const u16* __restrict__ qkvb, const int* __restrict__ pos,
              const float* __restrict__ qw, const float* __restrict__ kw,
              u16* __restrict__ qbf, u16* __restrict__ kbf) {
  const int wv = threadIdx.x >> 6, lane = threadIdx.x & 63;
  const int idx = blockIdx.x * 4 + wv;
  const int tt = idx / 24, hh = idx % 24;

  const int off = (hh < NH) ? hh * DH : KOFF + (hh - NH) * DH;
  const u16* base = qkvb + (size_t)tt * QKV_N + off;
  const float x1 = b2f(base[lane]);
  const float x2 = b2f(base[lane + 64]);

  float ss = x1 * x1 + x2 * x2;
#pragma unroll
  for (int o = 32; o > 0; o >>= 1) ss += __shfl_xor(ss, o);

  const float inv = rsqrtf(ss * (1.0f / DH) + EPS_RMS);
  const float* w = (hh < NH) ? qw : kw;
  const float n1 = x1 * inv * w[lane];
  const float n2 = x2 * inv * w[lane + 64];

  const float p    = (float)pos[tt];
  const float freq = powf(10000.0f, -(float)lane * (1.0f / 64.0f));
  const float ang  = p * freq;
  const float c = cosf(ang), s = sinf(ang);
  const float o1 = n1 * c - n2 * s;
  const float o2 = n2 * c + n1 * s;

  if (hh < NH) {
    u16* dst = qbf + ((size_t)tt * NH + hh) * DH;
    dst[lane]      = f2b(o1);
    dst[lane + 64] = f2b(o2);
  } else {
    const int u = (tt & 7) << 3;
    u16* dst = kbf + ((size_t)tt * NKV + (hh - NH)) * DH;
    dst[lane ^ u]        = f2b(o1);
    dst[(lane ^ u) + 64] = f2b(o2);
  }
}

// ---------------------------------------------------------------------------
// V transpose+cast: qkv v-region -> vT [NKV][128 d][T] bf16, with t
// pre-swizzled per d: pos_t = t ^ ((d&7)<<3).
// ---------------------------------------------------------------------------
__global__ __launch_bounds__(256)
void vtrans(const u16* __restrict__ qkvb, u16* __restrict__ vT) {
  __shared__ u16 td[128][40];     // [d][32 t], rows 80 B (16B-aligned cols)
  const int kvh = blockIdx.y;
  const int t0  = blockIdx.x * 32;
  const int f   = threadIdx.x;
  {
    const int r = f >> 3, c0 = (f & 7) * 16;
    const u16* src = qkvb + (size_t)(t0 + r) * QKV_N + VOFF + kvh * DH + c0;
    bf16x8 a = *(const bf16x8*)src;
    bf16x8 b = *(const bf16x8*)(src + 8);
#pragma unroll
    for (int j = 0; j < 8; ++j) td[c0 + j][r]     = ((u16*)&a)[j];
#pragma unroll
    for (int j = 0; j < 8; ++j) td[c0 + 8 + j][r] = ((u16*)&b)[j];
  }
  __syncthreads();
  {
    const int d = f >> 1, half = f & 1;
    const int sw = (d & 7) << 3;
    u16* orow = vT + (size_t)(kvh * DH + d) * T_SEQ;
#pragma unroll
    for (int g = 0; g < 2; ++g) {
      const int tb = t0 + half * 16 + g * 8;
      *(bf16x8*)(orow + (tb ^ sw)) = *(const bf16x8*)(&td[d][half * 16 + g * 8]);
    }
  }
}

// ---------------------------------------------------------------------------
// MFMA flash attention. Block = (q-tile 64, head). 4 waves, wave wv owns
// q rows q0+wv*16..+15. KV tiles of 64.  K LDS [64][128d] and V LDS
// [128d][64t] arrive XOR-swizzled via producers' pre-swizzled layouts.
// ---------------------------------------------------------------------------
__global__ __launch_bounds__(256)
void flash_mfma(const u16* __restrict__ qbf, const u16* __restrict__ kbf,
                const u16* __restrict__ vT, u16* __restrict__ obuf) {
  __shared__ u16 kls[64 * 128];     // 16 KB
  __shared__ u16 vls[128 * 64];     // 16 KB
  __shared__ u16 pls[4][16][72];    // 9 KB, per-wave P

  const int t = threadIdx.x, lane = t & 63, wv = t >> 6;
  const int lo = lane & 15, hi = lane >> 4;
  const int h = blockIdx.y, kvh = h >> 1;
  const int qt = gridDim.x - 1 - blockIdx.x;    // heavy tiles first
  const int q0 = qt * 64;

  // Q fragments straight from global (A-frag: row = lo, k = kk*32+hi*8+j)
  bf16x8 qf[4];
#pragma unroll
  for (int kk = 0; kk < 4; ++kk)
    qf[kk] = *(const bf16x8*)(qbf + ((size_t)(q0 + wv * 16 + lo) * NH + h) * DH
                              + kk * 32 + hi * 8);

  f32x4 oacc[8];
#pragma unroll
  for (int n = 0; n < 8; ++n) oacc[n] = (f32x4){0.f, 0.f, 0.f, 0.f};
  float mrow[4] = {-INFINITY, -INFINITY, -INFINITY, -INFINITY};
  float lrow[4] = {0.f, 0.f, 0.f, 0.f};

  for (int kt = 0; kt <= qt; ++kt) {
    const int k0 = kt * 64;
    // stage K (4 chunks/wave) and V (4 chunks/wave), 1 KB per chunk
#pragma unroll
    for (int c = 0; c < 4; ++c) {
      const int chunk = wv * 4 + c;
      const int krow  = chunk * 4 + (lane >> 4);
      g2l16(kls + chunk * 512 + lane * 8,
            kbf + ((size_t)(k0 + krow) * NKV + kvh) * DH + lo * 8);
      const int d = chunk * 8 + (lane >> 3);
      g2l16(vls + chunk * 512 + lane * 8,
            vT + (size_t)(kvh * DH + d) * T_SEQ + k0 + (lane & 7) * 8);
    }
    __syncthreads();

    // S = Q K^T : 4 col-blocks x 4 k-slices
    f32x4 sacc[4];
#pragma unroll
    for (int n = 0; n < 4; ++n) sacc[n] = (f32x4){0.f, 0.f, 0.f, 0.f};
#pragma unroll
    for (int n = 0; n < 4; ++n) {
      const int r = n * 16 + lo;                 // kv row (B col)
      const u16* kb = kls + r * 128;
#pragma unroll
      for (int kk = 0; kk < 4; ++kk) {
        const int offs = (kk * 32 + hi * 8) ^ ((r & 7) << 3);
        bf16x8 b = *(const bf16x8*)(kb + offs);
        sacc[n] = __builtin_amdgcn_mfma_f32_16x16x32_bf16(qf[kk], b, sacc[n], 0, 0, 0);
      }
    }

    // online softmax. lane owns S rows hi*4+r, cols n*16+lo.
    float pv[4][4], tm[4];
    const bool diag = (kt == qt);
#pragma unroll
    for (int r = 0; r < 4; ++r) {
      const int qi = q0 + wv * 16 + hi * 4 + r;
      float mx = -INFINITY;
#pragma unroll
      for (int n = 0; n < 4; ++n) {
        float s = sacc[n][r] * ATT_SCALE;
        if (diag && qi < k0 + n * 16 + lo) s = -INFINITY;
        pv[n][r] = s;
        mx = fmaxf(mx, s);
      }
      tm[r] = mx;
    }
#pragma unroll
    for (int o = 8; o > 0; o >>= 1)
#pragma unroll
      for (int r = 0; r < 4; ++r) tm[r] = fmaxf(tm[r], __shfl_xor(tm[r], o));

    float al[4], rs[4];
#pragma unroll
    for (int r = 0; r < 4; ++r) {
      const float mn = fmaxf(mrow[r], tm[r]);
      al[r] = __expf(mrow[r] - mn);
      mrow[r] = mn;
      rs[r] = 0.f;
    }
#pragma unroll
    for (int n = 0; n < 4; ++n)
#pragma unroll
      for (int r = 0; r < 4; ++r) {
        const float p = __expf(pv[n][r] - mrow[r]);
        pv[n][r] = p;
        rs[r] += p;
      }
#pragma unroll
    for (int o = 8; o > 0; o >>= 1)
#pragma unroll
      for (int r = 0; r < 4; ++r) rs[r] += __shfl_xor(rs[r], o);
#pragma unroll
    for (int r = 0; r < 4; ++r) lrow[r] = lrow[r] * al[r] + rs[r];
#pragma unroll
    for (int n = 0; n < 8; ++n)
#pragma unroll
      for (int r = 0; r < 4; ++r) oacc[n][r] *= al[r];

    // P -> LDS (bf16), per-wave private
#pragma unroll
    for (int n = 0; n < 4; ++n)
#pragma unroll
      for (int r = 0; r < 4; ++r)
        pls[wv][hi * 4 + r][n * 16 + lo] = f2b(pv[n][r]);

    // O += P V : A-frag row = lo, k = kk*32+hi*8+j
    bf16x8 pa[2];
#pragma unroll
    for (int kk = 0; kk < 2; ++kk)
      pa[kk] = *(const bf16x8*)(&pls[wv][lo][kk * 32 + hi * 8]);
#pragma unroll
    for (int n = 0; n < 8; ++n) {
      const int d = n * 16 + lo;
      const u16* vb = vls + d * 64;
#pragma unroll
      for (int kk = 0; kk < 2; ++kk) {
        const int offs = (kk * 32 + hi * 8) ^ ((d & 7) << 3);
        bf16x8 b = *(const bf16x8*)(vb + offs);
        oacc[n] = __builtin_amdgcn_mfma_f32_16x16x32_bf16(pa[kk], b, oacc[n], 0, 0, 0);
      }
    }
    __syncthreads();
  }

  float inv[4];
#pragma unroll
  for (int r = 0; r < 4; ++r) inv[r] = 1.0f / lrow[r];
#pragma unroll
  for (int n = 0; n < 8; ++n)
#pragma unroll
    for (int r = 0; r < 4; ++r)
      obuf[(size_t)(q0 + wv * 16 + hi * 4 + r) * HID + h * DH + n * 16 + lo] =
          f2b(oacc[n][r] * inv[r]);
}

// ---------------------------------------------------------------------------
extern "C" void kernel_launch(void* const* d_in, const int* in_sizes, int n_in,
                              void* d_out, int out_size, void* d_ws, size_t ws_size,
                              hipStream_t stream) {
  const float* x     = (const float*)d_in[0];
  const int*   pos   = (const int*)d_in[1];
  const float* w_qkv = (const float*)d_in[2];
  const float* qw    = (const float*)d_in[3];
  const float* kw    = (const float*)d_in[4];
  const float* w_o   = (const float*)d_in[5];
  float* out = (float*)d_out;

  // workspace: 48 MB, aliased by live-range (same footprint as round 1)
  char* w = (char*)d_ws;
  u16* xbf   = (u16*)w;                                   // 8 MB   [cast..gemm1]
  u16* qbf   = xbf;                                       //        [normrope..flash]
  u16* wqkvT = (u16*)(w + 8388608);                       // 16 MB  [tcast..gemm1]
  u16* kbf   = wqkvT;                                     // 4 MB   [normrope..flash]
  u16* vTb   = wqkvT + 2097152;                           // 4 MB   [vtrans..flash]
  u16* obuf  = wqkvT + 4194304;                           // 8 MB   [flash..gemm2]
  u16* woT   = (u16*)(w + 25165824);                      // 8 MB   [tcast..gemm2]
  u16* qkvbf = (u16*)(w + 33554432);                      // 16 MB  [gemm1..vtrans]

  cast_bf16<<<T_SEQ * HID / 4 / 256, 256, 0, stream>>>(x, xbf);
  tcast<<<dim3(QKV_N / 32, HID / 32), 256, 0, stream>>>(w_qkv, wqkvT, HID, QKV_N);
  tcast<<<dim3(HID / 32, HID / 32), 256, 0, stream>>>(w_o, woT, HID, HID);

  gemm_bt<1><<<dim3(QKV_N / 128, T_SEQ / 128), 256, 0, stream>>>(
      xbf, wqkvT, qkvbf, T_SEQ, QKV_N, HID);

  normrope<<<T_SEQ * 24 / 4, 256, 0, stream>>>(qkvbf, pos, qw, kw, qbf, kbf);
  vtrans<<<dim3(T_SEQ / 32, NKV), 256, 0, stream>>>(qkvbf, vTb);

  flash_mfma<<<dim3(T_SEQ / 64, NH), 256, 0, stream>>>(qbf, kbf, vTb, obuf);

  gemm_bt<0><<<dim3(HID / 128, T_SEQ / 128), 256, 0, stream>>>(
      obuf, woT, out, T_SEQ, HID, HID);
}

// Round 6
// 302.168 us; speedup vs baseline: 4.7005x; 1.0829x over previous
//
#include <hip/hip_runtime.h>
#include <hip/hip_bf16.h>
#include <math.h>

#define T_SEQ 2048
#define HID   2048
#define NH    16
#define NKV   8
#define DH    128
#define QKV_N 4096
#define KOFF  2048
#define VOFF  3072
#define EPS_RMS 1e-6f
#define ATT_SCALE 0.08838834764831845f   // 128^-0.5

typedef __attribute__((ext_vector_type(8))) short bf16x8;   // 8 bf16 = 4 VGPR
typedef __attribute__((ext_vector_type(4))) float f32x4;
typedef unsigned short u16;

__device__ __forceinline__ u16 f2b(float f) {               // fp32 -> bf16 RNE
  union { float f; unsigned u; } v; v.f = f;
  unsigned r = v.u + 0x7fff + ((v.u >> 16) & 1);
  return (u16)(r >> 16);
}
__device__ __forceinline__ float b2f(u16 x) {
  union { unsigned u; float f; } v; v.u = ((unsigned)x) << 16;
  return v.f;
}

// async global->LDS, 16B per lane. LDS dest must be linear base + lane*16.
__device__ __forceinline__ void g2l16(u16* l, const u16* g) {
#if __has_builtin(__builtin_amdgcn_global_load_lds)
  __builtin_amdgcn_global_load_lds(
      (const __attribute__((address_space(1))) unsigned int*)g,
      (__attribute__((address_space(3))) unsigned int*)l, 16, 0, 0);
#else
  *(float4*)l = *(const float4*)g;
#endif
}

// ---------------------------------------------------------------------------
// elementwise fp32 -> bf16 cast (x)
// ---------------------------------------------------------------------------
__global__ __launch_bounds__(256)
void cast_bf16(const float* __restrict__ src, u16* __restrict__ dst) {
  const int i = blockIdx.x * 256 + threadIdx.x;
  const float4 v = ((const float4*)src)[i];
  ushort4 o; o.x = f2b(v.x); o.y = f2b(v.y); o.z = f2b(v.z); o.w = f2b(v.w);
  ((ushort4*)dst)[i] = o;
}

// ---------------------------------------------------------------------------
// transpose + cast: src fp32 [R][C] -> dst bf16 [C][R]
// ---------------------------------------------------------------------------
__global__ __launch_bounds__(256)
void tcast(const float* __restrict__ src, u16* __restrict__ dst, int R, int C) {
  __shared__ u16 tile[32][36];
  const int br = blockIdx.y * 32, bc = blockIdx.x * 32;
  const int t = threadIdx.x;
  {
    const int r = t >> 3, c4 = (t & 7) * 4;
    const float4 v = *(const float4*)(src + (size_t)(br + r) * C + bc + c4);
    tile[c4 + 0][r] = f2b(v.x);
    tile[c4 + 1][r] = f2b(v.y);
    tile[c4 + 2][r] = f2b(v.z);
    tile[c4 + 3][r] = f2b(v.w);
  }
  __syncthreads();
  {
    const int c = t >> 3, r4 = (t & 7) * 4;
    ushort4 o = { tile[c][r4], tile[c][r4 + 1], tile[c][r4 + 2], tile[c][r4 + 3] };
    *(ushort4*)(dst + (size_t)(bc + c) * R + br + r4) = o;
  }
}

// ---------------------------------------------------------------------------
// bf16 MFMA GEMM: C[M][N] = A[M][K] @ BT[N][K]^T.  128x128 tile, BK=32,
// 4 waves, 4x4 16x16x32 fragments per wave.  BOUT: 1 = bf16 out, 0 = fp32.
// (unchanged — both GEMM dispatches < 94 us, near structure ceiling)
// ---------------------------------------------------------------------------
template<int BOUT>
__global__ __launch_bounds__(256)
void gemm_bt(const u16* __restrict__ A, const u16* __restrict__ BT,
             void* __restrict__ Cout, int M, int N, int K) {
  __shared__ u16 sA[128 * 32];   // [row][32 k] linear, 8 KB
  __shared__ u16 sB[128 * 32];

  const int t = threadIdx.x;
  const int lane = t & 63, wv = t >> 6;
  const int lo = lane & 15, hi = lane >> 4;
  const int bm = blockIdx.y * 128, bn = blockIdx.x * 128;
  const int wr = (wv >> 1) * 64, wc = (wv & 1) * 64;

  f32x4 acc[4][4];
#pragma unroll
  for (int m = 0; m < 4; ++m)
#pragma unroll
    for (int n = 0; n < 4; ++n) acc[m][n] = (f32x4){0.f, 0.f, 0.f, 0.f};

  // staging: wave wv fills LDS chunks {2wv, 2wv+1} (1 KB each = 16 rows)
  const int arow = wv * 32 + (lane >> 2);        // row for call 0
  const int koff = (lane & 3) * 8;               // bf16 offset in row
  const u16* gA = A + (size_t)(bm + arow) * K + koff;
  const u16* gB = BT + (size_t)(bn + arow) * K + koff;
  u16* lA = sA + wv * 1024 + lane * 8;
  u16* lB = sB + wv * 1024 + lane * 8;

  for (int k0 = 0; k0 < K; k0 += 32) {
    g2l16(lA,       gA + k0);
    g2l16(lA + 512, gA + (size_t)16 * K + k0);
    g2l16(lB,       gB + k0);
    g2l16(lB + 512, gB + (size_t)16 * K + k0);
    __syncthreads();

    bf16x8 af[4], bfr[4];
#pragma unroll
    for (int m = 0; m < 4; ++m)
      af[m] = *(const bf16x8*)(sA + (wr + m * 16 + lo) * 32 + hi * 8);
#pragma unroll
    for (int n = 0; n < 4; ++n)
      bfr[n] = *(const bf16x8*)(sB + (wc + n * 16 + lo) * 32 + hi * 8);
#pragma unroll
    for (int m = 0; m < 4; ++m)
#pragma unroll
      for (int n = 0; n < 4; ++n)
        acc[m][n] = __builtin_amdgcn_mfma_f32_16x16x32_bf16(af[m], bfr[n], acc[m][n], 0, 0, 0);
    __syncthreads();
  }

  // D layout: row = hi*4 + reg, col = lo
#pragma unroll
  for (int m = 0; m < 4; ++m)
#pragma unroll
    for (int n = 0; n < 4; ++n)
#pragma unroll
      for (int r = 0; r < 4; ++r) {
        const int row = bm + wr + m * 16 + hi * 4 + r;
        const int col = bn + wc + n * 16 + lo;
        if constexpr (BOUT)
          ((u16*)Cout)[(size_t)row * N + col] = f2b(acc[m][n][r]);
        else
          ((float*)Cout)[(size_t)row * N + col] = acc[m][n][r];
      }
}

// ---------------------------------------------------------------------------
// RMSNorm + RoPE on q,k (bf16 in, bf16 out). One wave per (t, head).
// powf -> exp2f (single v_exp_f32; freq err ~1ulp << bf16 rounding).
// ---------------------------------------------------------------------------
__global__ __launch_bounds__(256)
void normrope(const u16* __restrict__ qkvb, const int* __restrict__ pos,
              const float* __restrict__ qw, const float* __restrict__ kw,
              u16* __restrict__ qbf, u16* __restrict__ kbf) {
  const int wv = threadIdx.x >> 6, lane = threadIdx.x & 63;
  const int idx = blockIdx.x * 4 + wv;
  const int tt = idx / 24, hh = idx % 24;

  const int off = (hh < NH) ? hh * DH : KOFF + (hh - NH) * DH;
  const u16* base = qkvb + (size_t)tt * QKV_N + off;
  const float x1 = b2f(base[lane]);
  const float x2 = b2f(base[lane + 64]);

  float ss = x1 * x1 + x2 * x2;
#pragma unroll
  for (int o = 32; o > 0; o >>= 1) ss += __shfl_xor(ss, o);

  const float inv = rsqrtf(ss * (1.0f / DH) + EPS_RMS);
  const float* w = (hh < NH) ? qw : kw;
  const float n1 = x1 * inv * w[lane];
  const float n2 = x2 * inv * w[lane + 64];

  const float p    = (float)pos[tt];
  // 10000^(-lane/64) = 2^(-lane * log2(10000)/64)
  const float freq = exp2f((float)lane * -0.20762050593046014f);
  const float ang  = p * freq;
  const float c = cosf(ang), s = sinf(ang);
  const float o1 = n1 * c - n2 * s;
  const float o2 = n2 * c + n1 * s;

  if (hh < NH) {
    u16* dst = qbf + ((size_t)tt * NH + hh) * DH;
    dst[lane]      = f2b(o1);
    dst[lane + 64] = f2b(o2);
  } else {
    const int u = (tt & 7) << 3;
    u16* dst = kbf + ((size_t)tt * NKV + (hh - NH)) * DH;
    dst[lane ^ u]        = f2b(o1);
    dst[(lane ^ u) + 64] = f2b(o2);
  }
}

// ---------------------------------------------------------------------------
// V transpose+cast: qkv v-region -> vT [NKV][128 d][T] bf16, with t
// pre-swizzled per d: pos_t = t ^ ((d&7)<<3).  (unchanged)
// ---------------------------------------------------------------------------
__global__ __launch_bounds__(256)
void vtrans(const u16* __restrict__ qkvb, u16* __restrict__ vT) {
  __shared__ u16 td[128][40];     // [d][32 t], rows 80 B (16B-aligned cols)
  const int kvh = blockIdx.y;
  const int t0  = blockIdx.x * 32;
  const int f   = threadIdx.x;
  {
    const int r = f >> 3, c0 = (f & 7) * 16;
    const u16* src = qkvb + (size_t)(t0 + r) * QKV_N + VOFF + kvh * DH + c0;
    bf16x8 a = *(const bf16x8*)src;
    bf16x8 b = *(const bf16x8*)(src + 8);
#pragma unroll
    for (int j = 0; j < 8; ++j) td[c0 + j][r]     = ((u16*)&a)[j];
#pragma unroll
    for (int j = 0; j < 8; ++j) td[c0 + 8 + j][r] = ((u16*)&b)[j];
  }
  __syncthreads();
  {
    const int d = f >> 1, half = f & 1;
    const int sw = (d & 7) << 3;
    u16* orow = vT + (size_t)(kvh * DH + d) * T_SEQ;
#pragma unroll
    for (int g = 0; g < 2; ++g) {
      const int tb = t0 + half * 16 + g * 8;
      *(bf16x8*)(orow + (tb ^ sw)) = *(const bf16x8*)(&td[d][half * 16 + g * 8]);
    }
  }
}

// ---------------------------------------------------------------------------
// MFMA flash attention, software-pipelined (T3-minimum, single-buffered):
//   barrier#1 (after QK^T) -> issue stage_K(kt+1), flies under softmax+PV
//   barrier#2 (after PV)   -> issue stage_V(kt+1), flies under next QK^T
// Each barrier also drains vmcnt for the loads issued one half-iter earlier.
// XCD swizzle: XCD x runs q-heads {2x,2x+1} = kv-head x (1 MB K/V in its L2),
// heavy q-tiles first.  LDS unchanged (41984 B -> 3 blocks/CU).
// ---------------------------------------------------------------------------
__global__ __launch_bounds__(256)
void flash_mfma(const u16* __restrict__ qbf, const u16* __restrict__ kbf,
                const u16* __restrict__ vT, u16* __restrict__ obuf) {
  __shared__ u16 kls[64 * 128];     // 16 KB
  __shared__ u16 vls[128 * 64];     // 16 KB
  __shared__ u16 pls[4][16][72];    // 9 KB, per-wave P

  const int t = threadIdx.x, lane = t & 63, wv = t >> 6;
  const int lo = lane & 15, hi = lane >> 4;

  // XCD-aware swizzle: 512 blocks, 8 XCDs, bijective (512 % 8 == 0)
  const int id  = blockIdx.x;
  const int xcd = id & 7;
  const int idx = id >> 3;                      // 0..63
  const int h   = xcd * 2 + (idx & 1);          // kv-head == xcd
  const int qt  = 31 - (idx >> 1);              // heavy tiles first
  const int kvh = h >> 1;
  const int q0  = qt * 64;

  // Q fragments straight from global (A-frag: row = lo, k = kk*32+hi*8+j)
  bf16x8 qf[4];
#pragma unroll
  for (int kk = 0; kk < 4; ++kk)
    qf[kk] = *(const bf16x8*)(qbf + ((size_t)(q0 + wv * 16 + lo) * NH + h) * DH
                              + kk * 32 + hi * 8);

  f32x4 oacc[8];
#pragma unroll
  for (int n = 0; n < 8; ++n) oacc[n] = (f32x4){0.f, 0.f, 0.f, 0.f};
  float mrow[4] = {-INFINITY, -INFINITY, -INFINITY, -INFINITY};
  float lrow[4] = {0.f, 0.f, 0.f, 0.f};

  // staging helpers: wave wv fills chunks wv*4..wv*4+3 (1 KB each)
  auto stage_k = [&](int k0) {
#pragma unroll
    for (int c = 0; c < 4; ++c) {
      const int chunk = wv * 4 + c;
      g2l16(kls + chunk * 512 + lane * 8,
            kbf + ((size_t)(k0 + chunk * 4 + hi) * NKV + kvh) * DH + lo * 8);
    }
  };
  auto stage_v = [&](int k0) {
#pragma unroll
    for (int c = 0; c < 4; ++c) {
      const int chunk = wv * 4 + c;
      const int d = chunk * 8 + (lane >> 3);
      g2l16(vls + chunk * 512 + lane * 8,
            vT + (size_t)(kvh * DH + d) * T_SEQ + k0 + (lane & 7) * 8);
    }
  };

  stage_k(0);
  stage_v(0);
  __syncthreads();

  for (int kt = 0; kt <= qt; ++kt) {
    const int k0 = kt * 64;

    // S = Q K^T : 4 col-blocks x 4 k-slices (reads kls)
    f32x4 sacc[4];
#pragma unroll
    for (int n = 0; n < 4; ++n) sacc[n] = (f32x4){0.f, 0.f, 0.f, 0.f};
    __builtin_amdgcn_s_setprio(1);
#pragma unroll
    for (int n = 0; n < 4; ++n) {
      const int r = n * 16 + lo;                 // kv row (B col)
      const u16* kb = kls + r * 128;
#pragma unroll
      for (int kk = 0; kk < 4; ++kk) {
        const int offs = (kk * 32 + hi * 8) ^ ((r & 7) << 3);
        bf16x8 b = *(const bf16x8*)(kb + offs);
        sacc[n] = __builtin_amdgcn_mfma_f32_16x16x32_bf16(qf[kk], b, sacc[n], 0, 0, 0);
      }
    }
    __builtin_amdgcn_s_setprio(0);

    __syncthreads();                 // all waves done with kls; drains V(kt) loads
    if (kt < qt) stage_k(k0 + 64);   // K(kt+1) flies under softmax + PV

    // online softmax. lane owns S rows hi*4+r, cols n*16+lo.
    float pv[4][4], tm[4];
    const bool diag = (kt == qt);
#pragma unroll
    for (int r = 0; r < 4; ++r) {
      const int qi = q0 + wv * 16 + hi * 4 + r;
      float mx = -INFINITY;
#pragma unroll
      for (int n = 0; n < 4; ++n) {
        float s = sacc[n][r] * ATT_SCALE;
        if (diag && qi < k0 + n * 16 + lo) s = -INFINITY;
        pv[n][r] = s;
        mx = fmaxf(mx, s);
      }
      tm[r] = mx;
    }
#pragma unroll
    for (int o = 8; o > 0; o >>= 1)
#pragma unroll
      for (int r = 0; r < 4; ++r) tm[r] = fmaxf(tm[r], __shfl_xor(tm[r], o));

    float al[4], rs[4];
#pragma unroll
    for (int r = 0; r < 4; ++r) {
      const float mn = fmaxf(mrow[r], tm[r]);
      al[r] = __expf(mrow[r] - mn);
      mrow[r] = mn;
      rs[r] = 0.f;
    }
#pragma unroll
    for (int n = 0; n < 4; ++n)
#pragma unroll
      for (int r = 0; r < 4; ++r) {
        const float p = __expf(pv[n][r] - mrow[r]);
        pv[n][r] = p;
        rs[r] += p;
      }
#pragma unroll
    for (int o = 8; o > 0; o >>= 1)
#pragma unroll
      for (int r = 0; r < 4; ++r) rs[r] += __shfl_xor(rs[r], o);
#pragma unroll
    for (int r = 0; r < 4; ++r) lrow[r] = lrow[r] * al[r] + rs[r];
#pragma unroll
    for (int n = 0; n < 8; ++n)
#pragma unroll
      for (int r = 0; r < 4; ++r) oacc[n][r] *= al[r];

    // P -> LDS (bf16), per-wave private (same-wave write->read, lgkm-ordered)
#pragma unroll
    for (int n = 0; n < 4; ++n)
#pragma unroll
      for (int r = 0; r < 4; ++r)
        pls[wv][hi * 4 + r][n * 16 + lo] = f2b(pv[n][r]);

    // O += P V : A-frag row = lo, k = kk*32+hi*8+j (reads vls)
    bf16x8 pa[2];
#pragma unroll
    for (int kk = 0; kk < 2; ++kk)
      pa[kk] = *(const bf16x8*)(&pls[wv][lo][kk * 32 + hi * 8]);
    __builtin_amdgcn_s_setprio(1);
#pragma unroll
    for (int n = 0; n < 8; ++n) {
      const int d = n * 16 + lo;
      const u16* vb = vls + d * 64;
#pragma unroll
      for (int kk = 0; kk < 2; ++kk) {
        const int offs = (kk * 32 + hi * 8) ^ ((d & 7) << 3);
        bf16x8 b = *(const bf16x8*)(vb + offs);
        oacc[n] = __builtin_amdgcn_mfma_f32_16x16x32_bf16(pa[kk], b, oacc[n], 0, 0, 0);
      }
    }
    __builtin_amdgcn_s_setprio(0);

    __syncthreads();                 // all waves done with vls; drains K(kt+1)
    if (kt < qt) stage_v(k0 + 64);   // V(kt+1) flies under next QK^T + softmax
  }

  float inv[4];
#pragma unroll
  for (int r = 0; r < 4; ++r) inv[r] = 1.0f / lrow[r];
#pragma unroll
  for (int n = 0; n < 8; ++n)
#pragma unroll
    for (int r = 0; r < 4; ++r)
      obuf[(size_t)(q0 + wv * 16 + hi * 4 + r) * HID + h * DH + n * 16 + lo] =
          f2b(oacc[n][r] * inv[r]);
}

// ---------------------------------------------------------------------------
extern "C" void kernel_launch(void* const* d_in, const int* in_sizes, int n_in,
                              void* d_out, int out_size, void* d_ws, size_t ws_size,
                              hipStream_t stream) {
  const float* x     = (const float*)d_in[0];
  const int*   pos   = (const int*)d_in[1];
  const float* w_qkv = (const float*)d_in[2];
  const float* qw    = (const float*)d_in[3];
  const float* kw    = (const float*)d_in[4];
  const float* w_o   = (const float*)d_in[5];
  float* out = (float*)d_out;

  // workspace: 48 MB, aliased by live-range
  char* w = (char*)d_ws;
  u16* xbf   = (u16*)w;                                   // 8 MB   [cast..gemm1]
  u16* qbf   = xbf;                                       //        [normrope..flash]
  u16* wqkvT = (u16*)(w + 8388608);                       // 16 MB  [tcast..gemm1]
  u16* kbf   = wqkvT;                                     // 4 MB   [normrope..flash]
  u16* vTb   = wqkvT + 2097152;                           // 4 MB   [vtrans..flash]
  u16* obuf  = wqkvT + 4194304;                           // 8 MB   [flash..gemm2]
  u16* woT   = (u16*)(w + 25165824);                      // 8 MB   [tcast..gemm2]
  u16* qkvbf = (u16*)(w + 33554432);                      // 16 MB  [gemm1..vtrans]

  cast_bf16<<<T_SEQ * HID / 4 / 256, 256, 0, stream>>>(x, xbf);
  tcast<<<dim3(QKV_N / 32, HID / 32), 256, 0, stream>>>(w_qkv, wqkvT, HID, QKV_N);
  tcast<<<dim3(HID / 32, HID / 32), 256, 0, stream>>>(w_o, woT, HID, HID);

  gemm_bt<1><<<dim3(QKV_N / 128, T_SEQ / 128), 256, 0, stream>>>(
      xbf, wqkvT, qkvbf, T_SEQ, QKV_N, HID);

  normrope<<<T_SEQ * 24 / 4, 256, 0, stream>>>(qkvbf, pos, qw, kw, qbf, kbf);
  vtrans<<<dim3(T_SEQ / 32, NKV), 256, 0, stream>>>(qkvbf, vTb);

  flash_mfma<<<dim3(T_SEQ / 64 * NH), 256, 0, stream>>>(qbf, kbf, vTb, obuf);

  gemm_bt<0><<<dim3(HID / 128, T_SEQ / 128), 256, 0, stream>>>(
      obuf, woT, out, T_SEQ, HID, HID);
}

// Round 7
// 285.480 us; speedup vs baseline: 4.9753x; 1.0585x over previous
//
#include <hip/hip_runtime.h>
#include <hip/hip_bf16.h>
#include <math.h>

#define T_SEQ 2048
#define HID   2048
#define NH    16
#define NKV   8
#define DH    128
#define QKV_N 4096
#define KOFF  2048
#define VOFF  3072
#define EPS_RMS 1e-6f
#define ATT_SCALE 0.08838834764831845f   // 128^-0.5

typedef __attribute__((ext_vector_type(8))) short bf16x8;   // 8 bf16 = 4 VGPR
typedef __attribute__((ext_vector_type(4))) float f32x4;
typedef unsigned short u16;

__device__ __forceinline__ u16 f2b(float f) {               // fp32 -> bf16 RNE
  union { float f; unsigned u; } v; v.f = f;
  unsigned r = v.u + 0x7fff + ((v.u >> 16) & 1);
  return (u16)(r >> 16);
}
__device__ __forceinline__ float b2f(u16 x) {
  union { unsigned u; float f; } v; v.u = ((unsigned)x) << 16;
  return v.f;
}

// async global->LDS, 16B per lane. LDS dest must be linear base + lane*16.
__device__ __forceinline__ void g2l16(u16* l, const u16* g) {
#if __has_builtin(__builtin_amdgcn_global_load_lds)
  __builtin_amdgcn_global_load_lds(
      (const __attribute__((address_space(1))) unsigned int*)g,
      (__attribute__((address_space(3))) unsigned int*)l, 16, 0, 0);
#else
  *(float4*)l = *(const float4*)g;
#endif
}

// ---------------------------------------------------------------------------
// elementwise fp32 -> bf16 cast (x)
// ---------------------------------------------------------------------------
__global__ __launch_bounds__(256)
void cast_bf16(const float* __restrict__ src, u16* __restrict__ dst) {
  const int i = blockIdx.x * 256 + threadIdx.x;
  const float4 v = ((const float4*)src)[i];
  ushort4 o; o.x = f2b(v.x); o.y = f2b(v.y); o.z = f2b(v.z); o.w = f2b(v.w);
  ((ushort4*)dst)[i] = o;
}

// ---------------------------------------------------------------------------
// transpose + cast: src fp32 [R][C] -> dst bf16 [C][R]
// ---------------------------------------------------------------------------
__global__ __launch_bounds__(256)
void tcast(const float* __restrict__ src, u16* __restrict__ dst, int R, int C) {
  __shared__ u16 tile[32][36];
  const int br = blockIdx.y * 32, bc = blockIdx.x * 32;
  const int t = threadIdx.x;
  {
    const int r = t >> 3, c4 = (t & 7) * 4;
    const float4 v = *(const float4*)(src + (size_t)(br + r) * C + bc + c4);
    tile[c4 + 0][r] = f2b(v.x);
    tile[c4 + 1][r] = f2b(v.y);
    tile[c4 + 2][r] = f2b(v.z);
    tile[c4 + 3][r] = f2b(v.w);
  }
  __syncthreads();
  {
    const int c = t >> 3, r4 = (t & 7) * 4;
    ushort4 o = { tile[c][r4], tile[c][r4 + 1], tile[c][r4 + 2], tile[c][r4 + 3] };
    *(ushort4*)(dst + (size_t)(bc + c) * R + br + r4) = o;
  }
}

// ---------------------------------------------------------------------------
// bf16 MFMA GEMM: C[M][N] = A[M][K] @ BT[N][K]^T.  128x128 tile, BK=32,
// 4 waves, 4x4 16x16x32 fragments per wave.  BOUT: 1 = bf16 out, 0 = fp32.
// (unchanged)
// ---------------------------------------------------------------------------
template<int BOUT>
__global__ __launch_bounds__(256)
void gemm_bt(const u16* __restrict__ A, const u16* __restrict__ BT,
             void* __restrict__ Cout, int M, int N, int K) {
  __shared__ u16 sA[128 * 32];   // [row][32 k] linear, 8 KB
  __shared__ u16 sB[128 * 32];

  const int t = threadIdx.x;
  const int lane = t & 63, wv = t >> 6;
  const int lo = lane & 15, hi = lane >> 4;
  const int bm = blockIdx.y * 128, bn = blockIdx.x * 128;
  const int wr = (wv >> 1) * 64, wc = (wv & 1) * 64;

  f32x4 acc[4][4];
#pragma unroll
  for (int m = 0; m < 4; ++m)
#pragma unroll
    for (int n = 0; n < 4; ++n) acc[m][n] = (f32x4){0.f, 0.f, 0.f, 0.f};

  const int arow = wv * 32 + (lane >> 2);
  const int koff = (lane & 3) * 8;
  const u16* gA = A + (size_t)(bm + arow) * K + koff;
  const u16* gB = BT + (size_t)(bn + arow) * K + koff;
  u16* lA = sA + wv * 1024 + lane * 8;
  u16* lB = sB + wv * 1024 + lane * 8;

  for (int k0 = 0; k0 < K; k0 += 32) {
    g2l16(lA,       gA + k0);
    g2l16(lA + 512, gA + (size_t)16 * K + k0);
    g2l16(lB,       gB + k0);
    g2l16(lB + 512, gB + (size_t)16 * K + k0);
    __syncthreads();

    bf16x8 af[4], bfr[4];
#pragma unroll
    for (int m = 0; m < 4; ++m)
      af[m] = *(const bf16x8*)(sA + (wr + m * 16 + lo) * 32 + hi * 8);
#pragma unroll
    for (int n = 0; n < 4; ++n)
      bfr[n] = *(const bf16x8*)(sB + (wc + n * 16 + lo) * 32 + hi * 8);
#pragma unroll
    for (int m = 0; m < 4; ++m)
#pragma unroll
      for (int n = 0; n < 4; ++n)
        acc[m][n] = __builtin_amdgcn_mfma_f32_16x16x32_bf16(af[m], bfr[n], acc[m][n], 0, 0, 0);
    __syncthreads();
  }

#pragma unroll
  for (int m = 0; m < 4; ++m)
#pragma unroll
    for (int n = 0; n < 4; ++n)
#pragma unroll
      for (int r = 0; r < 4; ++r) {
        const int row = bm + wr + m * 16 + hi * 4 + r;
        const int col = bn + wc + n * 16 + lo;
        if constexpr (BOUT)
          ((u16*)Cout)[(size_t)row * N + col] = f2b(acc[m][n][r]);
        else
          ((float*)Cout)[(size_t)row * N + col] = acc[m][n][r];
      }
}

// ---------------------------------------------------------------------------
// RMSNorm + RoPE on q,k (bf16 in, bf16 out). One wave per (t, head).
// ---------------------------------------------------------------------------
__global__ __launch_bounds__(256)
void normrope(const u16* __restrict__ qkvb, const int* __restrict__ pos,
              const float* __restrict__ qw, const float* __restrict__ kw,
              u16* __restrict__ qbf, u16* __restrict__ kbf) {
  const int wv = threadIdx.x >> 6, lane = threadIdx.x & 63;
  const int idx = blockIdx.x * 4 + wv;
  const int tt = idx / 24, hh = idx % 24;

  const int off = (hh < NH) ? hh * DH : KOFF + (hh - NH) * DH;
  const u16* base = qkvb + (size_t)tt * QKV_N + off;
  const float x1 = b2f(base[lane]);
  const float x2 = b2f(base[lane + 64]);

  float ss = x1 * x1 + x2 * x2;
#pragma unroll
  for (int o = 32; o > 0; o >>= 1) ss += __shfl_xor(ss, o);

  const float inv = rsqrtf(ss * (1.0f / DH) + EPS_RMS);
  const float* w = (hh < NH) ? qw : kw;
  const float n1 = x1 * inv * w[lane];
  const float n2 = x2 * inv * w[lane + 64];

  const float p    = (float)pos[tt];
  const float freq = exp2f((float)lane * -0.20762050593046014f);
  const float ang  = p * freq;
  const float c = cosf(ang), s = sinf(ang);
  const float o1 = n1 * c - n2 * s;
  const float o2 = n2 * c + n1 * s;

  if (hh < NH) {
    u16* dst = qbf + ((size_t)tt * NH + hh) * DH;
    dst[lane]      = f2b(o1);
    dst[lane + 64] = f2b(o2);
  } else {
    const int u = (tt & 7) << 3;
    u16* dst = kbf + ((size_t)tt * NKV + (hh - NH)) * DH;
    dst[lane ^ u]        = f2b(o1);
    dst[(lane ^ u) + 64] = f2b(o2);
  }
}

// ---------------------------------------------------------------------------
// V transpose+cast (unchanged)
// ---------------------------------------------------------------------------
__global__ __launch_bounds__(256)
void vtrans(const u16* __restrict__ qkvb, u16* __restrict__ vT) {
  __shared__ u16 td[128][40];
  const int kvh = blockIdx.y;
  const int t0  = blockIdx.x * 32;
  const int f   = threadIdx.x;
  {
    const int r = f >> 3, c0 = (f & 7) * 16;
    const u16* src = qkvb + (size_t)(t0 + r) * QKV_N + VOFF + kvh * DH + c0;
    bf16x8 a = *(const bf16x8*)src;
    bf16x8 b = *(const bf16x8*)(src + 8);
#pragma unroll
    for (int j = 0; j < 8; ++j) td[c0 + j][r]     = ((u16*)&a)[j];
#pragma unroll
    for (int j = 0; j < 8; ++j) td[c0 + 8 + j][r] = ((u16*)&b)[j];
  }
  __syncthreads();
  {
    const int d = f >> 1, half = f & 1;
    const int sw = (d & 7) << 3;
    u16* orow = vT + (size_t)(kvh * DH + d) * T_SEQ;
#pragma unroll
    for (int g = 0; g < 2; ++g) {
      const int tb = t0 + half * 16 + g * 8;
      *(bf16x8*)(orow + (tb ^ sw)) = *(const bf16x8*)(&td[d][half * 16 + g * 8]);
    }
  }
}

// ---------------------------------------------------------------------------
// MFMA flash attention with KV-SPLIT (flash-decoding style).
// qt >= 8: two blocks each do half the kt range; partials (unnormalized O
// bf16 + per-row m,l fp32) -> workspace; merge_split combines.
// qt < 8: single block, writes obuf directly.  Inner loop code UNCHANGED
// from round 6 (pipelined stage_k/stage_v, setprio, swizzled LDS).
// Grid 896 = 8 XCDs x 112; kv-head-per-XCD swizzle, heavy parts first.
// ---------------------------------------------------------------------------
__global__ __launch_bounds__(256)
void flash_mfma(const u16* __restrict__ qbf, const u16* __restrict__ kbf,
                const u16* __restrict__ vT, u16* __restrict__ obuf,
                u16* __restrict__ pO, float* __restrict__ ml) {
  __shared__ u16 kls[64 * 128];     // 16 KB
  __shared__ u16 vls[128 * 64];     // 16 KB
  __shared__ u16 pls[4][16][72];    // 9 KB, per-wave P

  const int t = threadIdx.x, lane = t & 63, wv = t >> 6;
  const int lo = lane & 15, hi = lane >> 4;

  // block mapping: id -> (h, qt, part, kt range)
  const int id  = blockIdx.x;                   // 0..895
  const int xcd = id & 7;
  const int j   = id >> 3;                      // 0..111
  const int h   = xcd * 2 + (j & 1);            // kv-head == xcd
  const int s   = j >> 1;                       // 0..55, heavy first
  int qt, part, kt0, kt1, split;
  if (s < 48) {                                 // qt 31..8, 2 parts each
    qt = 31 - (s >> 1); part = s & 1; split = 1;
    const int half = (qt + 1) >> 1;
    kt0 = part ? half : 0;
    kt1 = part ? qt : half - 1;
  } else {                                      // qt 7..0, single
    qt = 55 - s; part = 0; split = 0; kt0 = 0; kt1 = qt;
  }
  const int kvh = h >> 1;
  const int q0  = qt * 64;

  // Q fragments straight from global (A-frag: row = lo, k = kk*32+hi*8+j)
  bf16x8 qf[4];
#pragma unroll
  for (int kk = 0; kk < 4; ++kk)
    qf[kk] = *(const bf16x8*)(qbf + ((size_t)(q0 + wv * 16 + lo) * NH + h) * DH
                              + kk * 32 + hi * 8);

  f32x4 oacc[8];
#pragma unroll
  for (int n = 0; n < 8; ++n) oacc[n] = (f32x4){0.f, 0.f, 0.f, 0.f};
  float mrow[4] = {-INFINITY, -INFINITY, -INFINITY, -INFINITY};
  float lrow[4] = {0.f, 0.f, 0.f, 0.f};

  auto stage_k = [&](int k0) {
#pragma unroll
    for (int c = 0; c < 4; ++c) {
      const int chunk = wv * 4 + c;
      g2l16(kls + chunk * 512 + lane * 8,
            kbf + ((size_t)(k0 + chunk * 4 + hi) * NKV + kvh) * DH + lo * 8);
    }
  };
  auto stage_v = [&](int k0) {
#pragma unroll
    for (int c = 0; c < 4; ++c) {
      const int chunk = wv * 4 + c;
      const int d = chunk * 8 + (lane >> 3);
      g2l16(vls + chunk * 512 + lane * 8,
            vT + (size_t)(kvh * DH + d) * T_SEQ + k0 + (lane & 7) * 8);
    }
  };

  stage_k(kt0 * 64);
  stage_v(kt0 * 64);
  __syncthreads();

  for (int kt = kt0; kt <= kt1; ++kt) {
    const int k0 = kt * 64;

    // S = Q K^T
    f32x4 sacc[4];
#pragma unroll
    for (int n = 0; n < 4; ++n) sacc[n] = (f32x4){0.f, 0.f, 0.f, 0.f};
    __builtin_amdgcn_s_setprio(1);
#pragma unroll
    for (int n = 0; n < 4; ++n) {
      const int r = n * 16 + lo;
      const u16* kb = kls + r * 128;
#pragma unroll
      for (int kk = 0; kk < 4; ++kk) {
        const int offs = (kk * 32 + hi * 8) ^ ((r & 7) << 3);
        bf16x8 b = *(const bf16x8*)(kb + offs);
        sacc[n] = __builtin_amdgcn_mfma_f32_16x16x32_bf16(qf[kk], b, sacc[n], 0, 0, 0);
      }
    }
    __builtin_amdgcn_s_setprio(0);

    __syncthreads();                    // all waves done with kls; drains V(kt)
    if (kt < kt1) stage_k(k0 + 64);     // K(kt+1) flies under softmax + PV

    // online softmax
    float pv[4][4], tm[4];
    const bool diag = (kt == qt);
#pragma unroll
    for (int r = 0; r < 4; ++r) {
      const int qi = q0 + wv * 16 + hi * 4 + r;
      float mx = -INFINITY;
#pragma unroll
      for (int n = 0; n < 4; ++n) {
        float sv = sacc[n][r] * ATT_SCALE;
        if (diag && qi < k0 + n * 16 + lo) sv = -INFINITY;
        pv[n][r] = sv;
        mx = fmaxf(mx, sv);
      }
      tm[r] = mx;
    }
#pragma unroll
    for (int o = 8; o > 0; o >>= 1)
#pragma unroll
      for (int r = 0; r < 4; ++r) tm[r] = fmaxf(tm[r], __shfl_xor(tm[r], o));

    float al[4], rs[4];
#pragma unroll
    for (int r = 0; r < 4; ++r) {
      const float mn = fmaxf(mrow[r], tm[r]);
      al[r] = __expf(mrow[r] - mn);
      mrow[r] = mn;
      rs[r] = 0.f;
    }
#pragma unroll
    for (int n = 0; n < 4; ++n)
#pragma unroll
      for (int r = 0; r < 4; ++r) {
        const float p = __expf(pv[n][r] - mrow[r]);
        pv[n][r] = p;
        rs[r] += p;
      }
#pragma unroll
    for (int o = 8; o > 0; o >>= 1)
#pragma unroll
      for (int r = 0; r < 4; ++r) rs[r] += __shfl_xor(rs[r], o);
#pragma unroll
    for (int r = 0; r < 4; ++r) lrow[r] = lrow[r] * al[r] + rs[r];
#pragma unroll
    for (int n = 0; n < 8; ++n)
#pragma unroll
      for (int r = 0; r < 4; ++r) oacc[n][r] *= al[r];

    // P -> LDS (bf16), per-wave private
#pragma unroll
    for (int n = 0; n < 4; ++n)
#pragma unroll
      for (int r = 0; r < 4; ++r)
        pls[wv][hi * 4 + r][n * 16 + lo] = f2b(pv[n][r]);

    // O += P V
    bf16x8 pa[2];
#pragma unroll
    for (int kk = 0; kk < 2; ++kk)
      pa[kk] = *(const bf16x8*)(&pls[wv][lo][kk * 32 + hi * 8]);
    __builtin_amdgcn_s_setprio(1);
#pragma unroll
    for (int n = 0; n < 8; ++n) {
      const int d = n * 16 + lo;
      const u16* vb = vls + d * 64;
#pragma unroll
      for (int kk = 0; kk < 2; ++kk) {
        const int offs = (kk * 32 + hi * 8) ^ ((d & 7) << 3);
        bf16x8 b = *(const bf16x8*)(vb + offs);
        oacc[n] = __builtin_amdgcn_mfma_f32_16x16x32_bf16(pa[kk], b, oacc[n], 0, 0, 0);
      }
    }
    __builtin_amdgcn_s_setprio(0);

    __syncthreads();                    // all waves done with vls; drains K(kt+1)
    if (kt < kt1) stage_v(k0 + 64);     // V(kt+1) flies under next QK^T
  }

  if (split) {
    // partials: pO[part][h][prow][128] bf16 unnormalized; ml[part][h][prow][2]
    const size_t rbase = (size_t)(part * 16 + h) * 1536
                       + (size_t)(qt - 8) * 64 + wv * 16;
#pragma unroll
    for (int n = 0; n < 8; ++n)
#pragma unroll
      for (int r = 0; r < 4; ++r)
        pO[(rbase + hi * 4 + r) * 128 + n * 16 + lo] = f2b(oacc[n][r]);
    if (lo == 0) {
#pragma unroll
      for (int r = 0; r < 4; ++r) {
        ml[(rbase + hi * 4 + r) * 2 + 0] = mrow[r];
        ml[(rbase + hi * 4 + r) * 2 + 1] = lrow[r];
      }
    }
  } else {
    float inv[4];
#pragma unroll
    for (int r = 0; r < 4; ++r) inv[r] = 1.0f / lrow[r];
#pragma unroll
    for (int n = 0; n < 8; ++n)
#pragma unroll
      for (int r = 0; r < 4; ++r)
        obuf[(size_t)(q0 + wv * 16 + hi * 4 + r) * HID + h * DH + n * 16 + lo] =
            f2b(oacc[n][r] * inv[r]);
  }
}

// ---------------------------------------------------------------------------
// merge the two KV-split partials:  O = (e^{mA-m} OA + e^{mB-m} OB) / l
// 24576 rows (h, prow); block = 256 thr = 16 rows x 16 lanes x bf16x8.
// ---------------------------------------------------------------------------
__global__ __launch_bounds__(256)
void merge_split(const u16* __restrict__ pO, const float* __restrict__ ml,
                 u16* __restrict__ obuf) {
  const int tid = threadIdx.x;
  const int rl = tid >> 4, lane16 = tid & 15;
  const int r = blockIdx.x * 16 + rl;           // 0..24575
  const int h = r / 1536, prow = r % 1536;
  const int trow = 512 + prow;                  // qt>=8 rows start at t=512
  const size_t iA = (size_t)h * 1536 + prow;
  const size_t iB = (size_t)(16 + h) * 1536 + prow;
  const float mA = ml[iA * 2], lA = ml[iA * 2 + 1];
  const float mB = ml[iB * 2], lB = ml[iB * 2 + 1];
  const float m  = fmaxf(mA, mB);
  const float a  = __expf(mA - m), b = __expf(mB - m);
  const float inv = 1.0f / (lA * a + lB * b);
  const float ca = a * inv, cb = b * inv;
  bf16x8 va = *(const bf16x8*)(pO + iA * 128 + lane16 * 8);
  bf16x8 vb = *(const bf16x8*)(pO + iB * 128 + lane16 * 8);
  u16 o[8];
#pragma unroll
  for (int k = 0; k < 8; ++k)
    o[k] = f2b(ca * b2f(((const u16*)&va)[k]) + cb * b2f(((const u16*)&vb)[k]));
  *(bf16x8*)(obuf + (size_t)trow * HID + h * DH + lane16 * 8) = *(bf16x8*)o;
}

// ---------------------------------------------------------------------------
extern "C" void kernel_launch(void* const* d_in, const int* in_sizes, int n_in,
                              void* d_out, int out_size, void* d_ws, size_t ws_size,
                              hipStream_t stream) {
  const float* x     = (const float*)d_in[0];
  const int*   pos   = (const int*)d_in[1];
  const float* w_qkv = (const float*)d_in[2];
  const float* qw    = (const float*)d_in[3];
  const float* kw    = (const float*)d_in[4];
  const float* w_o   = (const float*)d_in[5];
  float* out = (float*)d_out;

  // workspace: < 48 MiB, aliased by live-range
  char* w = (char*)d_ws;
  u16* xbf   = (u16*)w;                                   // 8 MB   [cast..gemm1]
  u16* qbf   = xbf;                                       //        [normrope..flash]
  u16* wqkvT = (u16*)(w + 8388608);                       // 16 MB  [tcast..gemm1]
  u16* kbf   = wqkvT;                                     // 4 MB   [normrope..flash]
  u16* vTb   = wqkvT + 2097152;                           // 4 MB   [vtrans..flash]
  u16* obuf  = wqkvT + 4194304;                           // 8 MB   [flash..gemm2]
  u16* woT   = (u16*)(w + 25165824);                      // 8 MB   [tcast..gemm2]
  u16* qkvbf = (u16*)(w + 33554432);                      // 16 MB  [gemm1..vtrans]
  u16*   pO  = (u16*)(w + 33554432);                      // 12.6MB [flash..merge]
  float* ml  = (float*)(w + 46137344);                    // 0.8MB  [flash..merge]

  cast_bf16<<<T_SEQ * HID / 4 / 256, 256, 0, stream>>>(x, xbf);
  tcast<<<dim3(QKV_N / 32, HID / 32), 256, 0, stream>>>(w_qkv, wqkvT, HID, QKV_N);
  tcast<<<dim3(HID / 32, HID / 32), 256, 0, stream>>>(w_o, woT, HID, HID);

  gemm_bt<1><<<dim3(QKV_N / 128, T_SEQ / 128), 256, 0, stream>>>(
      xbf, wqkvT, qkvbf, T_SEQ, QKV_N, HID);

  normrope<<<T_SEQ * 24 / 4, 256, 0, stream>>>(qkvbf, pos, qw, kw, qbf, kbf);
  vtrans<<<dim3(T_SEQ / 32, NKV), 256, 0, stream>>>(qkvbf, vTb);

  flash_mfma<<<896, 256, 0, stream>>>(qbf, kbf, vTb, obuf, pO, ml);
  merge_split<<<1536, 256, 0, stream>>>(pO, ml, obuf);

  gemm_bt<0><<<dim3(HID / 128, T_SEQ / 128), 256, 0, stream>>>(
      obuf, woT, out, T_SEQ, HID, HID);
}

// Round 8
// 274.293 us; speedup vs baseline: 5.1782x; 1.0408x over previous
//
#include <hip/hip_runtime.h>
#include <hip/hip_bf16.h>
#include <math.h>

#define T_SEQ 2048
#define HID   2048
#define NH    16
#define NKV   8
#define DH    128
#define QKV_N 4096
#define KOFF  2048
#define VOFF  3072
#define EPS_RMS 1e-6f
#define ATT_SCALE 0.08838834764831845f   // 128^-0.5

typedef __attribute__((ext_vector_type(8))) short bf16x8;   // 8 bf16 = 4 VGPR
typedef __attribute__((ext_vector_type(4))) float f32x4;
typedef unsigned short u16;

__device__ __forceinline__ u16 f2b(float f) {               // fp32 -> bf16 RNE
  union { float f; unsigned u; } v; v.f = f;
  unsigned r = v.u + 0x7fff + ((v.u >> 16) & 1);
  return (u16)(r >> 16);
}
__device__ __forceinline__ float b2f(u16 x) {
  union { unsigned u; float f; } v; v.u = ((unsigned)x) << 16;
  return v.f;
}

// async global->LDS, 16B per lane. LDS dest must be linear base + lane*16.
__device__ __forceinline__ void g2l16(u16* l, const u16* g) {
#if __has_builtin(__builtin_amdgcn_global_load_lds)
  __builtin_amdgcn_global_load_lds(
      (const __attribute__((address_space(1))) unsigned int*)g,
      (__attribute__((address_space(3))) unsigned int*)l, 16, 0, 0);
#else
  *(float4*)l = *(const float4*)g;
#endif
}

// ---------------------------------------------------------------------------
// elementwise fp32 -> bf16 cast (x)
// ---------------------------------------------------------------------------
__global__ __launch_bounds__(256)
void cast_bf16(const float* __restrict__ src, u16* __restrict__ dst) {
  const int i = blockIdx.x * 256 + threadIdx.x;
  const float4 v = ((const float4*)src)[i];
  ushort4 o; o.x = f2b(v.x); o.y = f2b(v.y); o.z = f2b(v.z); o.w = f2b(v.w);
  ((ushort4*)dst)[i] = o;
}

// ---------------------------------------------------------------------------
// transpose + cast: src fp32 [R][C] -> dst bf16 [C][R]
// ---------------------------------------------------------------------------
__global__ __launch_bounds__(256)
void tcast(const float* __restrict__ src, u16* __restrict__ dst, int R, int C) {
  __shared__ u16 tile[32][36];
  const int br = blockIdx.y * 32, bc = blockIdx.x * 32;
  const int t = threadIdx.x;
  {
    const int r = t >> 3, c4 = (t & 7) * 4;
    const float4 v = *(const float4*)(src + (size_t)(br + r) * C + bc + c4);
    tile[c4 + 0][r] = f2b(v.x);
    tile[c4 + 1][r] = f2b(v.y);
    tile[c4 + 2][r] = f2b(v.z);
    tile[c4 + 3][r] = f2b(v.w);
  }
  __syncthreads();
  {
    const int c = t >> 3, r4 = (t & 7) * 4;
    ushort4 o = { tile[c][r4], tile[c][r4 + 1], tile[c][r4 + 2], tile[c][r4 + 3] };
    *(ushort4*)(dst + (size_t)(bc + c) * R + br + r4) = o;
  }
}

// ---------------------------------------------------------------------------
// bf16 MFMA GEMM: C[M][N] = A[M][K] @ BT[N][K]^T.  Tile 128 x BN, K-step BK,
// 4 waves; wave tile 64 x BN/2.  BOUT: 1 = bf16 out, 0 = fp32.
//   gemm1: BN=128, BK=64  (half the barrier drains, 32 MFMA/wave/iter)
//   gemm2: BN=64,  BK=32  (512 blocks -> 2 blocks/CU)
// ---------------------------------------------------------------------------
template<int BOUT, int BN, int BK>
__global__ __launch_bounds__(256)
void gemm_bt(const u16* __restrict__ A, const u16* __restrict__ BT,
             void* __restrict__ Cout, int M, int N, int K) {
  __shared__ u16 sA[128 * BK];
  __shared__ u16 sB[BN * BK];

  constexpr int RPC = 512 / BK;        // rows per 1KB staging chunk
  constexpr int LPR = BK / 8;          // lanes per row (8 u16 per lane)
  constexpr int ACW = 128 / RPC / 4;   // A chunks per wave
  constexpr int BCW = BN / RPC / 4;    // B chunks per wave
  constexpr int WC  = BN / 2;          // wave tile cols
  constexpr int NF  = WC / 16;         // N fragments
  constexpr int KF  = BK / 32;         // K fragments

  const int t = threadIdx.x;
  const int lane = t & 63, wv = t >> 6;
  const int lo = lane & 15, hi = lane >> 4;
  const int bm = blockIdx.y * 128, bn = blockIdx.x * BN;
  const int wr = (wv >> 1) * 64, wc = (wv & 1) * WC;

  const int crow = lane / LPR;           // row within chunk
  const int ccol = (lane % LPR) * 8;     // k offset within row

  f32x4 acc[4][NF];
#pragma unroll
  for (int m = 0; m < 4; ++m)
#pragma unroll
    for (int n = 0; n < NF; ++n) acc[m][n] = (f32x4){0.f, 0.f, 0.f, 0.f};

  for (int k0 = 0; k0 < K; k0 += BK) {
#pragma unroll
    for (int c = 0; c < ACW; ++c) {
      const int chunk = wv * ACW + c;
      g2l16(sA + chunk * 512 + lane * 8,
            A + (size_t)(bm + chunk * RPC + crow) * K + k0 + ccol);
    }
#pragma unroll
    for (int c = 0; c < BCW; ++c) {
      const int chunk = wv * BCW + c;
      g2l16(sB + chunk * 512 + lane * 8,
            BT + (size_t)(bn + chunk * RPC + crow) * K + k0 + ccol);
    }
    __syncthreads();

    bf16x8 af[4][KF], bfr[NF][KF];
#pragma unroll
    for (int m = 0; m < 4; ++m)
#pragma unroll
      for (int kf = 0; kf < KF; ++kf)
        af[m][kf] = *(const bf16x8*)(sA + (wr + m * 16 + lo) * BK + kf * 32 + hi * 8);
#pragma unroll
    for (int n = 0; n < NF; ++n)
#pragma unroll
      for (int kf = 0; kf < KF; ++kf)
        bfr[n][kf] = *(const bf16x8*)(sB + (wc + n * 16 + lo) * BK + kf * 32 + hi * 8);
#pragma unroll
    for (int m = 0; m < 4; ++m)
#pragma unroll
      for (int n = 0; n < NF; ++n)
#pragma unroll
        for (int kf = 0; kf < KF; ++kf)
          acc[m][n] = __builtin_amdgcn_mfma_f32_16x16x32_bf16(af[m][kf], bfr[n][kf],
                                                              acc[m][n], 0, 0, 0);
    __syncthreads();
  }

  // D layout: row = hi*4 + reg, col = lo
#pragma unroll
  for (int m = 0; m < 4; ++m)
#pragma unroll
    for (int n = 0; n < NF; ++n)
#pragma unroll
      for (int r = 0; r < 4; ++r) {
        const int row = bm + wr + m * 16 + hi * 4 + r;
        const int col = bn + wc + n * 16 + lo;
        if constexpr (BOUT)
          ((u16*)Cout)[(size_t)row * N + col] = f2b(acc[m][n][r]);
        else
          ((float*)Cout)[(size_t)row * N + col] = acc[m][n][r];
      }
}

// ---------------------------------------------------------------------------
// RMSNorm + RoPE on q,k (bf16 in, bf16 out). One wave per (t, head).
// ---------------------------------------------------------------------------
__global__ __launch_bounds__(256)
void normrope(const u16* __restrict__ qkvb, const int* __restrict__ pos,
              const float* __restrict__ qw, const float* __restrict__ kw,
              u16* __restrict__ qbf, u16* __restrict__ kbf) {
  const int wv = threadIdx.x >> 6, lane = threadIdx.x & 63;
  const int idx = blockIdx.x * 4 + wv;
  const int tt = idx / 24, hh = idx % 24;

  const int off = (hh < NH) ? hh * DH : KOFF + (hh - NH) * DH;
  const u16* base = qkvb + (size_t)tt * QKV_N + off;
  const float x1 = b2f(base[lane]);
  const float x2 = b2f(base[lane + 64]);

  float ss = x1 * x1 + x2 * x2;
#pragma unroll
  for (int o = 32; o > 0; o >>= 1) ss += __shfl_xor(ss, o);

  const float inv = rsqrtf(ss * (1.0f / DH) + EPS_RMS);
  const float* w = (hh < NH) ? qw : kw;
  const float n1 = x1 * inv * w[lane];
  const float n2 = x2 * inv * w[lane + 64];

  const float p    = (float)pos[tt];
  const float freq = exp2f((float)lane * -0.20762050593046014f);
  const float ang  = p * freq;
  const float c = cosf(ang), s = sinf(ang);
  const float o1 = n1 * c - n2 * s;
  const float o2 = n2 * c + n1 * s;

  if (hh < NH) {
    u16* dst = qbf + ((size_t)tt * NH + hh) * DH;
    dst[lane]      = f2b(o1);
    dst[lane + 64] = f2b(o2);
  } else {
    const int u = (tt & 7) << 3;
    u16* dst = kbf + ((size_t)tt * NKV + (hh - NH)) * DH;
    dst[lane ^ u]        = f2b(o1);
    dst[(lane ^ u) + 64] = f2b(o2);
  }
}

// ---------------------------------------------------------------------------
// V transpose+cast (unchanged)
// ---------------------------------------------------------------------------
__global__ __launch_bounds__(256)
void vtrans(const u16* __restrict__ qkvb, u16* __restrict__ vT) {
  __shared__ u16 td[128][40];
  const int kvh = blockIdx.y;
  const int t0  = blockIdx.x * 32;
  const int f   = threadIdx.x;
  {
    const int r = f >> 3, c0 = (f & 7) * 16;
    const u16* src = qkvb + (size_t)(t0 + r) * QKV_N + VOFF + kvh * DH + c0;
    bf16x8 a = *(const bf16x8*)src;
    bf16x8 b = *(const bf16x8*)(src + 8);
#pragma unroll
    for (int j = 0; j < 8; ++j) td[c0 + j][r]     = ((u16*)&a)[j];
#pragma unroll
    for (int j = 0; j < 8; ++j) td[c0 + 8 + j][r] = ((u16*)&b)[j];
  }
  __syncthreads();
  {
    const int d = f >> 1, half = f & 1;
    const int sw = (d & 7) << 3;
    u16* orow = vT + (size_t)(kvh * DH + d) * T_SEQ;
#pragma unroll
    for (int g = 0; g < 2; ++g) {
      const int tb = t0 + half * 16 + g * 8;
      *(bf16x8*)(orow + (tb ^ sw)) = *(const bf16x8*)(&td[d][half * 16 + g * 8]);
    }
  }
}

// ---------------------------------------------------------------------------
// MFMA flash attention with KV-SPLIT (unchanged from round 7)
// ---------------------------------------------------------------------------
__global__ __launch_bounds__(256)
void flash_mfma(const u16* __restrict__ qbf, const u16* __restrict__ kbf,
                const u16* __restrict__ vT, u16* __restrict__ obuf,
                u16* __restrict__ pO, float* __restrict__ ml) {
  __shared__ u16 kls[64 * 128];     // 16 KB
  __shared__ u16 vls[128 * 64];     // 16 KB
  __shared__ u16 pls[4][16][72];    // 9 KB, per-wave P

  const int t = threadIdx.x, lane = t & 63, wv = t >> 6;
  const int lo = lane & 15, hi = lane >> 4;

  const int id  = blockIdx.x;                   // 0..895
  const int xcd = id & 7;
  const int j   = id >> 3;                      // 0..111
  const int h   = xcd * 2 + (j & 1);            // kv-head == xcd
  const int s   = j >> 1;                       // 0..55, heavy first
  int qt, part, kt0, kt1, split;
  if (s < 48) {                                 // qt 31..8, 2 parts each
    qt = 31 - (s >> 1); part = s & 1; split = 1;
    const int half = (qt + 1) >> 1;
    kt0 = part ? half : 0;
    kt1 = part ? qt : half - 1;
  } else {                                      // qt 7..0, single
    qt = 55 - s; part = 0; split = 0; kt0 = 0; kt1 = qt;
  }
  const int kvh = h >> 1;
  const int q0  = qt * 64;

  bf16x8 qf[4];
#pragma unroll
  for (int kk = 0; kk < 4; ++kk)
    qf[kk] = *(const bf16x8*)(qbf + ((size_t)(q0 + wv * 16 + lo) * NH + h) * DH
                              + kk * 32 + hi * 8);

  f32x4 oacc[8];
#pragma unroll
  for (int n = 0; n < 8; ++n) oacc[n] = (f32x4){0.f, 0.f, 0.f, 0.f};
  float mrow[4] = {-INFINITY, -INFINITY, -INFINITY, -INFINITY};
  float lrow[4] = {0.f, 0.f, 0.f, 0.f};

  auto stage_k = [&](int k0) {
#pragma unroll
    for (int c = 0; c < 4; ++c) {
      const int chunk = wv * 4 + c;
      g2l16(kls + chunk * 512 + lane * 8,
            kbf + ((size_t)(k0 + chunk * 4 + hi) * NKV + kvh) * DH + lo * 8);
    }
  };
  auto stage_v = [&](int k0) {
#pragma unroll
    for (int c = 0; c < 4; ++c) {
      const int chunk = wv * 4 + c;
      const int d = chunk * 8 + (lane >> 3);
      g2l16(vls + chunk * 512 + lane * 8,
            vT + (size_t)(kvh * DH + d) * T_SEQ + k0 + (lane & 7) * 8);
    }
  };

  stage_k(kt0 * 64);
  stage_v(kt0 * 64);
  __syncthreads();

  for (int kt = kt0; kt <= kt1; ++kt) {
    const int k0 = kt * 64;

    f32x4 sacc[4];
#pragma unroll
    for (int n = 0; n < 4; ++n) sacc[n] = (f32x4){0.f, 0.f, 0.f, 0.f};
    __builtin_amdgcn_s_setprio(1);
#pragma unroll
    for (int n = 0; n < 4; ++n) {
      const int r = n * 16 + lo;
      const u16* kb = kls + r * 128;
#pragma unroll
      for (int kk = 0; kk < 4; ++kk) {
        const int offs = (kk * 32 + hi * 8) ^ ((r & 7) << 3);
        bf16x8 b = *(const bf16x8*)(kb + offs);
        sacc[n] = __builtin_amdgcn_mfma_f32_16x16x32_bf16(qf[kk], b, sacc[n], 0, 0, 0);
      }
    }
    __builtin_amdgcn_s_setprio(0);

    __syncthreads();                    // all waves done with kls; drains V(kt)
    if (kt < kt1) stage_k(k0 + 64);     // K(kt+1) flies under softmax + PV

    float pv[4][4], tm[4];
    const bool diag = (kt == qt);
#pragma unroll
    for (int r = 0; r < 4; ++r) {
      const int qi = q0 + wv * 16 + hi * 4 + r;
      float mx = -INFINITY;
#pragma unroll
      for (int n = 0; n < 4; ++n) {
        float sv = sacc[n][r] * ATT_SCALE;
        if (diag && qi < k0 + n * 16 + lo) sv = -INFINITY;
        pv[n][r] = sv;
        mx = fmaxf(mx, sv);
      }
      tm[r] = mx;
    }
#pragma unroll
    for (int o = 8; o > 0; o >>= 1)
#pragma unroll
      for (int r = 0; r < 4; ++r) tm[r] = fmaxf(tm[r], __shfl_xor(tm[r], o));

    float al[4], rs[4];
#pragma unroll
    for (int r = 0; r < 4; ++r) {
      const float mn = fmaxf(mrow[r], tm[r]);
      al[r] = __expf(mrow[r] - mn);
      mrow[r] = mn;
      rs[r] = 0.f;
    }
#pragma unroll
    for (int n = 0; n < 4; ++n)
#pragma unroll
      for (int r = 0; r < 4; ++r) {
        const float p = __expf(pv[n][r] - mrow[r]);
        pv[n][r] = p;
        rs[r] += p;
      }
#pragma unroll
    for (int o = 8; o > 0; o >>= 1)
#pragma unroll
      for (int r = 0; r < 4; ++r) rs[r] += __shfl_xor(rs[r], o);
#pragma unroll
    for (int r = 0; r < 4; ++r) lrow[r] = lrow[r] * al[r] + rs[r];
#pragma unroll
    for (int n = 0; n < 8; ++n)
#pragma unroll
      for (int r = 0; r < 4; ++r) oacc[n][r] *= al[r];

#pragma unroll
    for (int n = 0; n < 4; ++n)
#pragma unroll
      for (int r = 0; r < 4; ++r)
        pls[wv][hi * 4 + r][n * 16 + lo] = f2b(pv[n][r]);

    bf16x8 pa[2];
#pragma unroll
    for (int kk = 0; kk < 2; ++kk)
      pa[kk] = *(const bf16x8*)(&pls[wv][lo][kk * 32 + hi * 8]);
    __builtin_amdgcn_s_setprio(1);
#pragma unroll
    for (int n = 0; n < 8; ++n) {
      const int d = n * 16 + lo;
      const u16* vb = vls + d * 64;
#pragma unroll
      for (int kk = 0; kk < 2; ++kk) {
        const int offs = (kk * 32 + hi * 8) ^ ((d & 7) << 3);
        bf16x8 b = *(const bf16x8*)(vb + offs);
        oacc[n] = __builtin_amdgcn_mfma_f32_16x16x32_bf16(pa[kk], b, oacc[n], 0, 0, 0);
      }
    }
    __builtin_amdgcn_s_setprio(0);

    __syncthreads();                    // all waves done with vls; drains K(kt+1)
    if (kt < kt1) stage_v(k0 + 64);     // V(kt+1) flies under next QK^T
  }

  if (split) {
    const size_t rbase = (size_t)(part * 16 + h) * 1536
                       + (size_t)(qt - 8) * 64 + wv * 16;
#pragma unroll
    for (int n = 0; n < 8; ++n)
#pragma unroll
      for (int r = 0; r < 4; ++r)
        pO[(rbase + hi * 4 + r) * 128 + n * 16 + lo] = f2b(oacc[n][r]);
    if (lo == 0) {
#pragma unroll
      for (int r = 0; r < 4; ++r) {
        ml[(rbase + hi * 4 + r) * 2 + 0] = mrow[r];
        ml[(rbase + hi * 4 + r) * 2 + 1] = lrow[r];
      }
    }
  } else {
    float inv[4];
#pragma unroll
    for (int r = 0; r < 4; ++r) inv[r] = 1.0f / lrow[r];
#pragma unroll
    for (int n = 0; n < 8; ++n)
#pragma unroll
      for (int r = 0; r < 4; ++r)
        obuf[(size_t)(q0 + wv * 16 + hi * 4 + r) * HID + h * DH + n * 16 + lo] =
            f2b(oacc[n][r] * inv[r]);
  }
}

// ---------------------------------------------------------------------------
// merge the two KV-split partials (unchanged)
// ---------------------------------------------------------------------------
__global__ __launch_bounds__(256)
void merge_split(const u16* __restrict__ pO, const float* __restrict__ ml,
                 u16* __restrict__ obuf) {
  const int tid = threadIdx.x;
  const int rl = tid >> 4, lane16 = tid & 15;
  const int r = blockIdx.x * 16 + rl;           // 0..24575
  const int h = r / 1536, prow = r % 1536;
  const int trow = 512 + prow;
  const size_t iA = (size_t)h * 1536 + prow;
  const size_t iB = (size_t)(16 + h) * 1536 + prow;
  const float mA = ml[iA * 2], lA = ml[iA * 2 + 1];
  const float mB = ml[iB * 2], lB = ml[iB * 2 + 1];
  const float m  = fmaxf(mA, mB);
  const float a  = __expf(mA - m), b = __expf(mB - m);
  const float inv = 1.0f / (lA * a + lB * b);
  const float ca = a * inv, cb = b * inv;
  bf16x8 va = *(const bf16x8*)(pO + iA * 128 + lane16 * 8);
  bf16x8 vb = *(const bf16x8*)(pO + iB * 128 + lane16 * 8);
  u16 o[8];
#pragma unroll
  for (int k = 0; k < 8; ++k)
    o[k] = f2b(ca * b2f(((const u16*)&va)[k]) + cb * b2f(((const u16*)&vb)[k]));
  *(bf16x8*)(obuf + (size_t)trow * HID + h * DH + lane16 * 8) = *(bf16x8*)o;
}

// ---------------------------------------------------------------------------
extern "C" void kernel_launch(void* const* d_in, const int* in_sizes, int n_in,
                              void* d_out, int out_size, void* d_ws, size_t ws_size,
                              hipStream_t stream) {
  const float* x     = (const float*)d_in[0];
  const int*   pos   = (const int*)d_in[1];
  const float* w_qkv = (const float*)d_in[2];
  const float* qw    = (const float*)d_in[3];
  const float* kw    = (const float*)d_in[4];
  const float* w_o   = (const float*)d_in[5];
  float* out = (float*)d_out;

  // workspace: < 48 MiB, aliased by live-range
  char* w = (char*)d_ws;
  u16* xbf   = (u16*)w;                                   // 8 MB   [cast..gemm1]
  u16* qbf   = xbf;                                       //        [normrope..flash]
  u16* wqkvT = (u16*)(w + 8388608);                       // 16 MB  [tcast..gemm1]
  u16* kbf   = wqkvT;                                     // 4 MB   [normrope..flash]
  u16* vTb   = wqkvT + 2097152;                           // 4 MB   [vtrans..flash]
  u16* obuf  = wqkvT + 4194304;                           // 8 MB   [flash..gemm2]
  u16* woT   = (u16*)(w + 25165824);                      // 8 MB   [tcast..gemm2]
  u16* qkvbf = (u16*)(w + 33554432);                      // 16 MB  [gemm1..vtrans]
  u16*   pO  = (u16*)(w + 33554432);                      // 12.6MB [flash..merge]
  float* ml  = (float*)(w + 46137344);                    // 0.8MB  [flash..merge]

  cast_bf16<<<T_SEQ * HID / 4 / 256, 256, 0, stream>>>(x, xbf);
  tcast<<<dim3(QKV_N / 32, HID / 32), 256, 0, stream>>>(w_qkv, wqkvT, HID, QKV_N);
  tcast<<<dim3(HID / 32, HID / 32), 256, 0, stream>>>(w_o, woT, HID, HID);

  // gemm1: BN=128, BK=64 (half barrier count)
  gemm_bt<1, 128, 64><<<dim3(QKV_N / 128, T_SEQ / 128), 256, 0, stream>>>(
      xbf, wqkvT, qkvbf, T_SEQ, QKV_N, HID);

  normrope<<<T_SEQ * 24 / 4, 256, 0, stream>>>(qkvbf, pos, qw, kw, qbf, kbf);
  vtrans<<<dim3(T_SEQ / 32, NKV), 256, 0, stream>>>(qkvbf, vTb);

  flash_mfma<<<896, 256, 0, stream>>>(qbf, kbf, vTb, obuf, pO, ml);
  merge_split<<<1536, 256, 0, stream>>>(pO, ml, obuf);

  // gemm2: BN=64, BK=32 (512 blocks -> 2 blocks/CU)
  gemm_bt<0, 64, 32><<<dim3(HID / 64, T_SEQ / 128), 256, 0, stream>>>(
      obuf, woT, out, T_SEQ, HID, HID);
}